// Round 2
// baseline (259.794 us; speedup 1.0000x reference)
//
#include <hip/hip_runtime.h>
#include <hip/hip_bf16.h>

// ---------- types ----------
typedef __attribute__((ext_vector_type(4))) float f32x4;
typedef __attribute__((ext_vector_type(8))) short bf16x8;   // 8 bf16 in 4 VGPRs
typedef unsigned short u16;
typedef unsigned int   u32;
typedef unsigned long long u64;

#define S_LEN 2048
#define HID   2048
#define NH    16
#define NKV   4
#define HD    128
#define DKV   512          // NKV*HD
#define QK_SCALE 0.08838834764831845f   // 1/sqrt(128)

__device__ __forceinline__ u16 f2bf(float x) {              // RNE f32 -> bf16 bits
    u32 u = __builtin_bit_cast(u32, x);
    u32 r = (u + 0x7fffu + ((u >> 16) & 1u)) >> 16;
    return (u16)r;
}
__device__ __forceinline__ float bf2f(u16 b) {
    u32 u = ((u32)b) << 16;
    return __builtin_bit_cast(float, u);
}
__device__ __forceinline__ void gload_lds16(const void* g, void* l) {
    __builtin_amdgcn_global_load_lds(
        (const __attribute__((address_space(1))) u32*)g,
        (__attribute__((address_space(3))) u32*)l, 16, 0, 0);
}

// ---------- dtype detection ----------
// flags[0] = 1 if inputs are f32 (incl. f32 holding bf16-rounded values), 0 if bf16
// flags[1] = mask element byte width (1 or 4)
__global__ void detect_kernel(const u32* x, const unsigned char* mask, int* flags) {
    int lane = threadIdx.x;
    int big = 0, nz = 0;
    for (int i = lane; i < 256; i += 64) {
        u16 lo = (u16)(x[i] & 0xffffu);
        int e = (lo >> 7) & 0xff;
        big |= (e >= 0x83);          // |bf16(lo)| >= 16 or NaN/Inf -> random mantissa -> f32
        nz  |= (lo != 0);
    }
    u64 bigb = __ballot(big);
    u64 nzb  = __ballot(nz);
    if (lane == 0) {
        flags[0] = (bigb != 0ull || nzb == 0ull) ? 1 : 0;
        flags[1] = (mask[2049] != 0) ? 1 : 4;   // row1,col1 True for 1-byte masks
    }
}

// ---------- per-row window start: start[i] = i+1 - count(true) ----------
__global__ void extract_start_kernel(const unsigned char* mask, int* start, const int* flags) {
    int i = blockIdx.x, lane = threadIdx.x;
    int w = flags[1];
    int cnt = 0;
    if (w == 1) {
        for (int j = lane; j < S_LEN; j += 64)
            cnt += (mask[(size_t)i * S_LEN + j] != 0);
    } else {
        const u32* m4 = (const u32*)mask;
        for (int j = lane; j < S_LEN; j += 64)
            cnt += (m4[(size_t)i * S_LEN + j] != 0);
    }
    #pragma unroll
    for (int off = 32; off; off >>= 1) cnt += __shfl_down(cnt, off);
    if (lane == 0) start[i] = i + 1 - cnt;
}

// ---------- convert (f32|bf16) -> bf16, contiguous ----------
__global__ void cvt_bf16_kernel(const void* in, u16* out, long n, const int* flags) {
    int isf32 = flags[0];
    long i = (long)blockIdx.x * blockDim.x + threadIdx.x;
    long stride = (long)gridDim.x * blockDim.x;
    if (isf32) {
        const float* p = (const float*)in;
        for (; i < n; i += stride) out[i] = f2bf(p[i]);
    } else {
        const u16* p = (const u16*)in;
        for (; i < n; i += stride) out[i] = p[i];
    }
}

// ---------- transpose + convert: W[K][N] -> WT[N][K] bf16 ----------
__global__ void transpose_cvt_kernel(const void* in, u16* out, int K, int N, const int* flags) {
    __shared__ float tile[32][33];
    int isf32 = flags[0];
    int n0 = blockIdx.x * 32, k0 = blockIdx.y * 32;
    for (int kk = threadIdx.y; kk < 32; kk += 8) {
        size_t idx = (size_t)(k0 + kk) * N + n0 + threadIdx.x;
        float v = isf32 ? ((const float*)in)[idx] : bf2f(((const u16*)in)[idx]);
        tile[kk][threadIdx.x] = v;
    }
    __syncthreads();
    for (int nn = threadIdx.y; nn < 32; nn += 8) {
        out[(size_t)(n0 + nn) * K + k0 + threadIdx.x] = f2bf(tile[threadIdx.x][nn]);
    }
}

// ---------- GEMM: C = A[M][K] * B  (B given as BT[N][K]), bf16 in; modes:
//  MODE 0: bf16 C[m*N+n]   MODE 1: bf16 scaled   MODE 2: bf16 transposed C[n*M+m]
//  MODE 3: f32  C[m*N+n]
template <int MODE>
__global__ __launch_bounds__(256) void gemm_bt_kernel(
        const u16* __restrict__ A, const u16* __restrict__ BT, void* __restrict__ Cv,
        int M, int N, int K, float scale)
{
    __shared__ char smem[32768];              // As[128][64] | Bs[128][64], XOR-swizzled
    const int tid = threadIdx.x;
    const int wave = tid >> 6, lane = tid & 63, g = lane >> 4, q = lane & 15;
    const int wr = wave >> 1, wc = wave & 1;
    const int m0 = blockIdx.y * 128, n0 = blockIdx.x * 128;

    f32x4 acc[4][4];
    #pragma unroll
    for (int i = 0; i < 4; i++)
        #pragma unroll
        for (int j = 0; j < 4; j++) acc[i][j] = (f32x4){0.f, 0.f, 0.f, 0.f};

    const int KT = K >> 6;
    for (int kt = 0; kt < KT; ++kt) {
        const int kbase = kt << 6;
        // stage A and BT tiles: 128 rows x 64 bf16 each; per-lane source chunk
        // pre-swizzled, LDS dest linear in lane order (global_load_lds rule)
        #pragma unroll
        for (int it = 0; it < 4; ++it) {
            int idx = it * 256 + tid;
            int row = idx >> 3, ch = idx & 7;
            int sch = ch ^ (row & 7);
            gload_lds16(A  + (size_t)(m0 + row) * K + kbase + sch * 8, smem + idx * 16);
            gload_lds16(BT + (size_t)(n0 + row) * K + kbase + sch * 8, smem + 16384 + idx * 16);
        }
        __syncthreads();
        #pragma unroll
        for (int kk = 0; kk < 2; ++kk) {
            bf16x8 af[4], bfr[4];
            #pragma unroll
            for (int i = 0; i < 4; i++) {
                int ra = wr * 64 + i * 16 + q;
                af[i]  = *(const bf16x8*)(smem + ra * 128 + (((kk * 4 + g) ^ (ra & 7)) * 16));
                int rb = wc * 64 + i * 16 + q;
                bfr[i] = *(const bf16x8*)(smem + 16384 + rb * 128 + (((kk * 4 + g) ^ (rb & 7)) * 16));
            }
            #pragma unroll
            for (int i = 0; i < 4; i++)
                #pragma unroll
                for (int j = 0; j < 4; j++)
                    acc[i][j] = __builtin_amdgcn_mfma_f32_16x16x32_bf16(af[i], bfr[j], acc[i][j], 0, 0, 0);
        }
        __syncthreads();
    }
    // epilogue: C row m = m0+wr*64+i*16+g*4+r, col n = n0+wc*64+j*16+q
    #pragma unroll
    for (int i = 0; i < 4; i++) {
        #pragma unroll
        for (int j = 0; j < 4; j++) {
            #pragma unroll
            for (int r = 0; r < 4; r++) {
                int m = m0 + wr * 64 + i * 16 + g * 4 + r;
                int n = n0 + wc * 64 + j * 16 + q;
                float v = acc[i][j][r];
                if (MODE == 1) v *= scale;
                if (MODE == 3)      ((float*)Cv)[(size_t)m * N + n] = v;
                else if (MODE == 2) ((u16*)Cv)[(size_t)n * M + m] = f2bf(v);
                else                ((u16*)Cv)[(size_t)m * N + n] = f2bf(v);
            }
        }
    }
}

// ---------- adaptive-window flash attention ----------
// Q[seq][NH*HD] (pre-scaled), K[seq][NKV*HD], Vt[NKV*HD][seq], O[seq][NH*HD], all bf16.
// grid (S/64, NH), block 256 = 4 waves; wave handles 16 q-rows.
__global__ __launch_bounds__(256) void attn_kernel(
        const u16* __restrict__ Q, const u16* __restrict__ Kb,
        const u16* __restrict__ Vt, u16* __restrict__ O, const int* __restrict__ start)
{
    __shared__ char psm[4 * 1280];            // per-wave P^T tile: 16 rows x pitch 80B
    const int tid = threadIdx.x, wave = tid >> 6, lane = tid & 63;
    const int g = lane >> 4, q = lane & 15;
    const int h = blockIdx.y, hk = h >> 2;
    const int r0 = blockIdx.x * 64 + wave * 16;
    const int qrow = r0 + q;

    // Q fragments (B-operand layout): lane holds Q[r0+q][kk*32 + g*8 + e]
    const u16* qp = Q + (size_t)qrow * HID + h * HD + g * 8;
    bf16x8 Qf[4];
    #pragma unroll
    for (int kk = 0; kk < 4; kk++) Qf[kk] = *(const bf16x8*)(qp + kk * 32);

    const int startq = start[qrow];
    int jlo = startq;
    #pragma unroll
    for (int off = 1; off < 16; off <<= 1) jlo = min(jlo, __shfl_xor(jlo, off));
    const int jend = r0 + 15;

    float m = -INFINITY, l = 0.f;
    f32x4 o[8];
    #pragma unroll
    for (int t = 0; t < 8; t++) o[t] = (f32x4){0.f, 0.f, 0.f, 0.f};

    char* prow = psm + wave * 1280 + q * 80;   // this lane's P^T row (by q)

    for (int j0 = (jlo & ~31); j0 <= jend; j0 += 32) {
        // S^T = K * Q^T for 2 halves of 16 keys
        f32x4 s[2];
        s[0] = (f32x4){0.f, 0.f, 0.f, 0.f};
        s[1] = (f32x4){0.f, 0.f, 0.f, 0.f};
        #pragma unroll
        for (int hf = 0; hf < 2; hf++) {
            int kj = j0 + hf * 16 + q; if (kj > S_LEN - 1) kj = S_LEN - 1;
            const u16* kp = Kb + (size_t)kj * DKV + hk * HD + g * 8;
            #pragma unroll
            for (int kk = 0; kk < 4; kk++) {
                bf16x8 Kf = *(const bf16x8*)(kp + kk * 32);
                s[hf] = __builtin_amdgcn_mfma_f32_16x16x32_bf16(Kf, Qf[kk], s[hf], 0, 0, 0);
            }
        }
        // mask + online softmax (col=q is the query; keys spread over g,regs,halves)
        float sv[8];
        float pmax = -INFINITY;
        #pragma unroll
        for (int hf = 0; hf < 2; hf++) {
            #pragma unroll
            for (int r = 0; r < 4; r++) {
                int j = j0 + hf * 16 + g * 4 + r;
                float x = s[hf][r];
                x = (j <= qrow && j >= startq) ? x : -INFINITY;
                sv[hf * 4 + r] = x;
                pmax = fmaxf(pmax, x);
            }
        }
        pmax = fmaxf(pmax, __shfl_xor(pmax, 16));
        pmax = fmaxf(pmax, __shfl_xor(pmax, 32));
        float mnew = fmaxf(m, pmax);
        float corr = (m == -INFINITY) ? 0.f : __expf(m - mnew);
        float ps = 0.f;
        u16 pb[8];
        #pragma unroll
        for (int t = 0; t < 8; t++) {
            float p = (sv[t] == -INFINITY) ? 0.f : __expf(sv[t] - mnew);
            ps += p;
            pb[t] = f2bf(p);
        }
        ps += __shfl_xor(ps, 16);
        ps += __shfl_xor(ps, 32);
        l = l * corr + ps;
        m = mnew;
        #pragma unroll
        for (int t = 0; t < 8; t++) {
            o[t][0] *= corr; o[t][1] *= corr; o[t][2] *= corr; o[t][3] *= corr;
        }
        // store P^T to LDS: row q, col jl = hf*16 + g*4 + r (bf16), two 8B writes
        #pragma unroll
        for (int hf = 0; hf < 2; hf++) {
            u64 w = (u64)pb[hf * 4 + 0] | ((u64)pb[hf * 4 + 1] << 16) |
                    ((u64)pb[hf * 4 + 2] << 32) | ((u64)pb[hf * 4 + 3] << 48);
            *(u64*)(prow + hf * 32 + g * 8) = w;
        }
        // PV: O^T[d][q] += Vt[d][j] * P^T[j][q]
        bf16x8 Pf = *(const bf16x8*)(psm + wave * 1280 + q * 80 + g * 16);
        int jv = j0 + g * 8; if (jv > S_LEN - 8) jv = S_LEN - 8;
        #pragma unroll
        for (int t = 0; t < 8; t++) {
            const u16* vp = Vt + (size_t)(hk * HD + t * 16 + q) * S_LEN + jv;
            bf16x8 Vf = *(const bf16x8*)vp;
            o[t] = __builtin_amdgcn_mfma_f32_16x16x32_bf16(Vf, Pf, o[t], 0, 0, 0);
        }
    }
    // epilogue: O[qrow][h*HD + d], d = t*16 + g*4 + r
    float inv = 1.0f / l;
    #pragma unroll
    for (int t = 0; t < 8; t++) {
        u64 w = (u64)f2bf(o[t][0] * inv) | ((u64)f2bf(o[t][1] * inv) << 16) |
                ((u64)f2bf(o[t][2] * inv) << 32) | ((u64)f2bf(o[t][3] * inv) << 48);
        *(u64*)(O + (size_t)qrow * HID + h * HD + t * 16 + g * 4) = w;
    }
}

// ---------- launch ----------
extern "C" void kernel_launch(void* const* d_in, const int* in_sizes, int n_in,
                              void* d_out, int out_size, void* d_ws, size_t ws_size,
                              hipStream_t stream)
{
    char* ws = (char*)d_ws;
    const size_t MB = 1024 * 1024;
    int* flags = (int*)(ws + 0);
    int* start = (int*)(ws + 1024);
    u16* Xbf = (u16*)(ws + 16384);
    u16* WqT = (u16*)(ws + 16384 + 8 * MB);
    u16* WkT = (u16*)(ws + 16384 + 16 * MB);
    u16* WvT = (u16*)(ws + 16384 + 18 * MB);
    u16* WoT = (u16*)(ws + 16384 + 20 * MB);
    u16* Qbf = (u16*)(ws + 16384 + 28 * MB);
    u16* Kbf = (u16*)(ws + 16384 + 36 * MB);
    u16* Vtb = (u16*)(ws + 16384 + 38 * MB);
    u16* Obf = (u16*)(ws + 16384 + 40 * MB);

    const void* X  = d_in[0];
    const unsigned char* mask = (const unsigned char*)d_in[1];
    const void* Wq = d_in[2];
    const void* Wk = d_in[3];
    const void* Wv = d_in[4];
    const void* Wo = d_in[5];

    detect_kernel<<<1, 64, 0, stream>>>((const u32*)X, mask, flags);
    extract_start_kernel<<<S_LEN, 64, 0, stream>>>(mask, start, flags);
    cvt_bf16_kernel<<<1024, 256, 0, stream>>>(X, Xbf, (long)S_LEN * HID, flags);
    transpose_cvt_kernel<<<dim3(HID / 32, HID / 32), dim3(32, 8), 0, stream>>>(Wq, WqT, HID, HID, flags);
    transpose_cvt_kernel<<<dim3(DKV / 32, HID / 32), dim3(32, 8), 0, stream>>>(Wk, WkT, HID, DKV, flags);
    transpose_cvt_kernel<<<dim3(DKV / 32, HID / 32), dim3(32, 8), 0, stream>>>(Wv, WvT, HID, DKV, flags);
    transpose_cvt_kernel<<<dim3(HID / 32, HID / 32), dim3(32, 8), 0, stream>>>(Wo, WoT, HID, HID, flags);

    gemm_bt_kernel<1><<<dim3(HID / 128, S_LEN / 128), 256, 0, stream>>>(Xbf, WqT, Qbf, S_LEN, HID, HID, QK_SCALE);
    gemm_bt_kernel<0><<<dim3(DKV / 128, S_LEN / 128), 256, 0, stream>>>(Xbf, WkT, Kbf, S_LEN, DKV, HID, 1.f);
    gemm_bt_kernel<2><<<dim3(DKV / 128, S_LEN / 128), 256, 0, stream>>>(Xbf, WvT, Vtb, S_LEN, DKV, HID, 1.f);

    attn_kernel<<<dim3(S_LEN / 64, NH), 256, 0, stream>>>(Qbf, Kbf, Vtb, Obf, start);

    gemm_bt_kernel<3><<<dim3(HID / 128, S_LEN / 128), 256, 0, stream>>>(Obf, WoT, d_out, S_LEN, HID, HID, 1.f);
}

// Round 3
// 204.465 us; speedup vs baseline: 1.2706x; 1.2706x over previous
//
#include <hip/hip_runtime.h>
#include <hip/hip_bf16.h>

// ---------- types ----------
typedef __attribute__((ext_vector_type(4))) float f32x4;
typedef __attribute__((ext_vector_type(8))) short bf16x8;   // 8 bf16 in 4 VGPRs
typedef unsigned short u16;
typedef unsigned int   u32;
typedef unsigned long long u64;

#define S_LEN 2048
#define HID   2048
#define NH    16
#define NKV   4
#define HD    128
#define DKV   512          // NKV*HD
#define QK_SCALE 0.08838834764831845f   // 1/sqrt(128)

__device__ __forceinline__ u16 f2bf(float x) {              // RNE f32 -> bf16 bits
    u32 u = __builtin_bit_cast(u32, x);
    u32 r = (u + 0x7fffu + ((u >> 16) & 1u)) >> 16;
    return (u16)r;
}
__device__ __forceinline__ float bf2f(u16 b) {
    u32 u = ((u32)b) << 16;
    return __builtin_bit_cast(float, u);
}
__device__ __forceinline__ void gload_lds16(const void* g, void* l) {
    __builtin_amdgcn_global_load_lds(
        (const __attribute__((address_space(1))) u32*)g,
        (__attribute__((address_space(3))) u32*)l, 16, 0, 0);
}

// ---------- dtype detection ----------
__global__ void detect_kernel(const u32* x, const unsigned char* mask, int* flags) {
    int lane = threadIdx.x;
    int big = 0, nz = 0;
    for (int i = lane; i < 256; i += 64) {
        u16 lo = (u16)(x[i] & 0xffffu);
        int e = (lo >> 7) & 0xff;
        big |= (e >= 0x83);
        nz  |= (lo != 0);
    }
    u64 bigb = __ballot(big);
    u64 nzb  = __ballot(nz);
    if (lane == 0) {
        flags[0] = (bigb != 0ull || nzb == 0ull) ? 1 : 0;   // 1 = f32 input
        flags[1] = (mask[2049] != 0) ? 1 : 4;               // mask elem width
    }
}

// ---------- per-row window start: start[i] = i+1 - count(true) ----------
__global__ void extract_start_kernel(const unsigned char* mask, int* start, const int* flags) {
    int i = blockIdx.x, lane = threadIdx.x;
    int w = flags[1];
    int cnt = 0;
    if (w == 1) {
        for (int j = lane; j < S_LEN; j += 64)
            cnt += (mask[(size_t)i * S_LEN + j] != 0);
    } else {
        const u32* m4 = (const u32*)mask;
        for (int j = lane; j < S_LEN; j += 64)
            cnt += (m4[(size_t)i * S_LEN + j] != 0);
    }
    #pragma unroll
    for (int off = 32; off; off >>= 1) cnt += __shfl_down(cnt, off);
    if (lane == 0) start[i] = i + 1 - cnt;
}

// ---------- convert (f32|bf16) -> bf16, contiguous ----------
__global__ void cvt_bf16_kernel(const void* in, u16* out, long n, const int* flags) {
    int isf32 = flags[0];
    long i = (long)blockIdx.x * blockDim.x + threadIdx.x;
    long stride = (long)gridDim.x * blockDim.x;
    if (isf32) {
        const float* p = (const float*)in;
        for (; i < n; i += stride) out[i] = f2bf(p[i]);
    } else {
        const u16* p = (const u16*)in;
        for (; i < n; i += stride) out[i] = p[i];
    }
}

// ---------- transpose + convert: W[K][N] -> WT[N][K] bf16 ----------
__global__ void transpose_cvt_kernel(const void* in, u16* out, int K, int N, const int* flags) {
    __shared__ float tile[32][33];
    int isf32 = flags[0];
    int n0 = blockIdx.x * 32, k0 = blockIdx.y * 32;
    for (int kk = threadIdx.y; kk < 32; kk += 8) {
        size_t idx = (size_t)(k0 + kk) * N + n0 + threadIdx.x;
        float v = isf32 ? ((const float*)in)[idx] : bf2f(((const u16*)in)[idx]);
        tile[kk][threadIdx.x] = v;
    }
    __syncthreads();
    for (int nn = threadIdx.y; nn < 32; nn += 8) {
        out[(size_t)(n0 + nn) * K + k0 + threadIdx.x] = f2bf(tile[threadIdx.x][nn]);
    }
}

// ================= fused QKV projection GEMM =================
// A[2048][2048] bf16, BT = WqT|WkT|WvT contiguous [3072][2048] bf16.
// cols 0..2047 -> Q (scaled), 2048..2559 -> K, 2560..3071 -> V^T.
__global__ __launch_bounds__(256) void gemm_qkv_kernel(
        const u16* __restrict__ A, const u16* __restrict__ BT,
        u16* __restrict__ Qo, u16* __restrict__ Ko, u16* __restrict__ Vto)
{
    __shared__ char smem[32768];
    const int tid = threadIdx.x;
    const int wave = tid >> 6, lane = tid & 63, g = lane >> 4, q = lane & 15;
    const int wr = wave >> 1, wc = wave & 1;
    const int m0 = blockIdx.y * 128, n0 = blockIdx.x * 128;
    const int K = HID;

    f32x4 acc[4][4];
    #pragma unroll
    for (int i = 0; i < 4; i++)
        #pragma unroll
        for (int j = 0; j < 4; j++) acc[i][j] = (f32x4){0.f, 0.f, 0.f, 0.f};

    for (int kt = 0; kt < (K >> 6); ++kt) {
        const int kbase = kt << 6;
        #pragma unroll
        for (int it = 0; it < 4; ++it) {
            int idx = it * 256 + tid;
            int row = idx >> 3, ch = idx & 7;
            int sch = ch ^ (row & 7);
            gload_lds16(A  + (size_t)(m0 + row) * K + kbase + sch * 8, smem + idx * 16);
            gload_lds16(BT + (size_t)(n0 + row) * K + kbase + sch * 8, smem + 16384 + idx * 16);
        }
        __syncthreads();
        #pragma unroll
        for (int kk = 0; kk < 2; ++kk) {
            bf16x8 af[4], bfr[4];
            #pragma unroll
            for (int i = 0; i < 4; i++) {
                int ra = wr * 64 + i * 16 + q;
                af[i]  = *(const bf16x8*)(smem + ra * 128 + (((kk * 4 + g) ^ (ra & 7)) * 16));
                int rb = wc * 64 + i * 16 + q;
                bfr[i] = *(const bf16x8*)(smem + 16384 + rb * 128 + (((kk * 4 + g) ^ (rb & 7)) * 16));
            }
            #pragma unroll
            for (int i = 0; i < 4; i++)
                #pragma unroll
                for (int j = 0; j < 4; j++)
                    acc[i][j] = __builtin_amdgcn_mfma_f32_16x16x32_bf16(af[i], bfr[j], acc[i][j], 0, 0, 0);
        }
        __syncthreads();
    }
    #pragma unroll
    for (int i = 0; i < 4; i++) {
        #pragma unroll
        for (int j = 0; j < 4; j++) {
            #pragma unroll
            for (int r = 0; r < 4; r++) {
                int m = m0 + wr * 64 + i * 16 + g * 4 + r;
                int n = n0 + wc * 64 + j * 16 + q;
                float v = acc[i][j][r];
                if (n0 < 2048)      Qo[(size_t)m * HID + n] = f2bf(v * QK_SCALE);
                else if (n0 < 2560) Ko[(size_t)m * DKV + (n - 2048)] = f2bf(v);
                else                Vto[(size_t)(n - 2560) * S_LEN + m] = f2bf(v);
            }
        }
    }
}

// ---------- GEMM: C = A[M][K]*B (BT[N][K]); MODE 0: bf16 out, MODE 3: f32 out ----------
template <int MODE>
__global__ __launch_bounds__(256) void gemm_bt_kernel(
        const u16* __restrict__ A, const u16* __restrict__ BT, void* __restrict__ Cv,
        int M, int N, int K, float scale)
{
    __shared__ char smem[32768];
    const int tid = threadIdx.x;
    const int wave = tid >> 6, lane = tid & 63, g = lane >> 4, q = lane & 15;
    const int wr = wave >> 1, wc = wave & 1;
    const int m0 = blockIdx.y * 128, n0 = blockIdx.x * 128;

    f32x4 acc[4][4];
    #pragma unroll
    for (int i = 0; i < 4; i++)
        #pragma unroll
        for (int j = 0; j < 4; j++) acc[i][j] = (f32x4){0.f, 0.f, 0.f, 0.f};

    for (int kt = 0; kt < (K >> 6); ++kt) {
        const int kbase = kt << 6;
        #pragma unroll
        for (int it = 0; it < 4; ++it) {
            int idx = it * 256 + tid;
            int row = idx >> 3, ch = idx & 7;
            int sch = ch ^ (row & 7);
            gload_lds16(A  + (size_t)(m0 + row) * K + kbase + sch * 8, smem + idx * 16);
            gload_lds16(BT + (size_t)(n0 + row) * K + kbase + sch * 8, smem + 16384 + idx * 16);
        }
        __syncthreads();
        #pragma unroll
        for (int kk = 0; kk < 2; ++kk) {
            bf16x8 af[4], bfr[4];
            #pragma unroll
            for (int i = 0; i < 4; i++) {
                int ra = wr * 64 + i * 16 + q;
                af[i]  = *(const bf16x8*)(smem + ra * 128 + (((kk * 4 + g) ^ (ra & 7)) * 16));
                int rb = wc * 64 + i * 16 + q;
                bfr[i] = *(const bf16x8*)(smem + 16384 + rb * 128 + (((kk * 4 + g) ^ (rb & 7)) * 16));
            }
            #pragma unroll
            for (int i = 0; i < 4; i++)
                #pragma unroll
                for (int j = 0; j < 4; j++)
                    acc[i][j] = __builtin_amdgcn_mfma_f32_16x16x32_bf16(af[i], bfr[j], acc[i][j], 0, 0, 0);
        }
        __syncthreads();
    }
    #pragma unroll
    for (int i = 0; i < 4; i++) {
        #pragma unroll
        for (int j = 0; j < 4; j++) {
            #pragma unroll
            for (int r = 0; r < 4; r++) {
                int m = m0 + wr * 64 + i * 16 + g * 4 + r;
                int n = n0 + wc * 64 + j * 16 + q;
                float v = acc[i][j][r] * scale;
                if (MODE == 3) ((float*)Cv)[(size_t)m * N + n] = v;
                else           ((u16*)Cv)[(size_t)m * N + n] = f2bf(v);
            }
        }
    }
}

// ================= adaptive-window flash attention, 4-way KV split =================
// grid (S/16, NH), block 256 = 4 waves. Each block: 16 q-rows of one head;
// waves split the key-tile range 4 ways; LDS merge of partial (m,l,O).
__global__ __launch_bounds__(256) void attn_kernel(
        const u16* __restrict__ Q, const u16* __restrict__ Kb,
        const u16* __restrict__ Vt, u16* __restrict__ O, const int* __restrict__ start)
{
    __shared__ float pbuf[3][16][132];   // partial O^T per wave 1..3: [q][d], padded
    __shared__ float mlbuf[3][16][2];
    __shared__ char  psm[4 * 1280];      // per-wave P^T staging
    const int tid = threadIdx.x, wave = tid >> 6, lane = tid & 63;
    const int g = lane >> 4, q = lane & 15;
    const int h = blockIdx.y, hk = h >> 2;
    const int r0 = blockIdx.x * 16;
    const int qrow = r0 + q;

    // Q fragments (B-operand layout): lane holds Q[r0+q][kk*32 + g*8 + e]
    const u16* qp = Q + (size_t)qrow * HID + h * HD + g * 8;
    bf16x8 Qf[4];
    #pragma unroll
    for (int kk = 0; kk < 4; kk++) Qf[kk] = *(const bf16x8*)(qp + kk * 32);

    const int startq = start[qrow];
    int jlo = startq;
    #pragma unroll
    for (int off = 1; off < 16; off <<= 1) jlo = min(jlo, __shfl_xor(jlo, off));
    const int jend = r0 + 15;
    const int jbase = jlo & ~31;
    const int nt = ((jend - jbase) >> 5) + 1;        // total 32-key tiles
    const int tA = (nt * wave) >> 2, tB = (nt * (wave + 1)) >> 2;

    float m = -INFINITY, l = 0.f;
    f32x4 o[8];
    #pragma unroll
    for (int t = 0; t < 8; t++) o[t] = (f32x4){0.f, 0.f, 0.f, 0.f};

    char* prow = psm + wave * 1280 + q * 80;

    for (int ti = tA; ti < tB; ++ti) {
        const int j0 = jbase + ti * 32;
        // --- load all K and V fragments for this tile up front (latency overlap) ---
        bf16x8 Kf[2][4], Vf[8];
        #pragma unroll
        for (int hf = 0; hf < 2; hf++) {
            int kj = j0 + hf * 16 + q; if (kj > S_LEN - 1) kj = S_LEN - 1;
            const u16* kp = Kb + (size_t)kj * DKV + hk * HD + g * 8;
            #pragma unroll
            for (int kk = 0; kk < 4; kk++) Kf[hf][kk] = *(const bf16x8*)(kp + kk * 32);
        }
        int jv = j0 + g * 8; if (jv > S_LEN - 8) jv = S_LEN - 8;
        #pragma unroll
        for (int t = 0; t < 8; t++)
            Vf[t] = *(const bf16x8*)(Vt + (size_t)(hk * HD + t * 16 + q) * S_LEN + jv);

        // --- S^T = K * Q^T ---
        f32x4 s[2];
        s[0] = (f32x4){0.f, 0.f, 0.f, 0.f};
        s[1] = (f32x4){0.f, 0.f, 0.f, 0.f};
        #pragma unroll
        for (int hf = 0; hf < 2; hf++)
            #pragma unroll
            for (int kk = 0; kk < 4; kk++)
                s[hf] = __builtin_amdgcn_mfma_f32_16x16x32_bf16(Kf[hf][kk], Qf[kk], s[hf], 0, 0, 0);

        // --- mask + online softmax ---
        float sv[8];
        float pmax = -INFINITY;
        #pragma unroll
        for (int hf = 0; hf < 2; hf++) {
            #pragma unroll
            for (int r = 0; r < 4; r++) {
                int j = j0 + hf * 16 + g * 4 + r;
                float x = s[hf][r];
                x = (j <= qrow && j >= startq) ? x : -INFINITY;
                sv[hf * 4 + r] = x;
                pmax = fmaxf(pmax, x);
            }
        }
        pmax = fmaxf(pmax, __shfl_xor(pmax, 16));
        pmax = fmaxf(pmax, __shfl_xor(pmax, 32));
        float mnew = fmaxf(m, pmax);
        float corr = (m == -INFINITY) ? 0.f : __expf(m - mnew);
        float ps = 0.f;
        u16 pb[8];
        #pragma unroll
        for (int t = 0; t < 8; t++) {
            float p = (sv[t] == -INFINITY) ? 0.f : __expf(sv[t] - mnew);
            ps += p;
            pb[t] = f2bf(p);
        }
        ps += __shfl_xor(ps, 16);
        ps += __shfl_xor(ps, 32);
        l = l * corr + ps;
        m = mnew;
        #pragma unroll
        for (int t = 0; t < 8; t++) {
            o[t][0] *= corr; o[t][1] *= corr; o[t][2] *= corr; o[t][3] *= corr;
        }
        // --- P^T to LDS (wave-local), read back as B-fragment ---
        #pragma unroll
        for (int hf = 0; hf < 2; hf++) {
            u64 w = (u64)pb[hf * 4 + 0] | ((u64)pb[hf * 4 + 1] << 16) |
                    ((u64)pb[hf * 4 + 2] << 32) | ((u64)pb[hf * 4 + 3] << 48);
            *(u64*)(prow + hf * 32 + g * 8) = w;
        }
        bf16x8 Pf = *(const bf16x8*)(psm + wave * 1280 + q * 80 + g * 16);
        // --- PV: O^T[d][q] += Vt[d][j] * P^T[j][q] ---
        #pragma unroll
        for (int t = 0; t < 8; t++)
            o[t] = __builtin_amdgcn_mfma_f32_16x16x32_bf16(Vf[t], Pf, o[t], 0, 0, 0);
    }

    // --- merge partials across waves ---
    if (wave != 0) {
        #pragma unroll
        for (int t = 0; t < 8; t++)
            *(f32x4*)&pbuf[wave - 1][q][t * 16 + g * 4] = o[t];
        if (g == 0) { mlbuf[wave - 1][q][0] = m; mlbuf[wave - 1][q][1] = l; }
    }
    __syncthreads();
    if (wave == 0) {
        #pragma unroll
        for (int w = 0; w < 3; w++) {
            float mw = mlbuf[w][q][0], lw = mlbuf[w][q][1];
            float mn = fmaxf(m, mw);
            float ca = (m  == -INFINITY) ? 0.f : __expf(m  - mn);
            float cb = (mw == -INFINITY) ? 0.f : __expf(mw - mn);
            l = l * ca + lw * cb;
            #pragma unroll
            for (int t = 0; t < 8; t++) {
                f32x4 ow = *(const f32x4*)&pbuf[w][q][t * 16 + g * 4];
                o[t] = o[t] * ca + ow * cb;
            }
            m = mn;
        }
        float inv = 1.0f / l;
        #pragma unroll
        for (int t = 0; t < 8; t++) {
            u64 w = (u64)f2bf(o[t][0] * inv) | ((u64)f2bf(o[t][1] * inv) << 16) |
                    ((u64)f2bf(o[t][2] * inv) << 32) | ((u64)f2bf(o[t][3] * inv) << 48);
            *(u64*)(O + (size_t)qrow * HID + h * HD + t * 16 + g * 4) = w;
        }
    }
}

// ---------- launch ----------
extern "C" void kernel_launch(void* const* d_in, const int* in_sizes, int n_in,
                              void* d_out, int out_size, void* d_ws, size_t ws_size,
                              hipStream_t stream)
{
    char* ws = (char*)d_ws;
    const size_t MB = 1024 * 1024;
    int* flags = (int*)(ws + 0);
    int* start = (int*)(ws + 1024);
    u16* Xbf = (u16*)(ws + 16384);
    u16* WqT = (u16*)(ws + 16384 + 8 * MB);    // [2048][2048]
    u16* WkT = (u16*)(ws + 16384 + 16 * MB);   // [512][2048] (contiguous after WqT)
    u16* WvT = (u16*)(ws + 16384 + 18 * MB);   // [512][2048]
    u16* WoT = (u16*)(ws + 16384 + 20 * MB);
    u16* Qbf = (u16*)(ws + 16384 + 28 * MB);
    u16* Kbf = (u16*)(ws + 16384 + 36 * MB);
    u16* Vtb = (u16*)(ws + 16384 + 38 * MB);
    u16* Obf = (u16*)(ws + 16384 + 40 * MB);

    const void* X  = d_in[0];
    const unsigned char* mask = (const unsigned char*)d_in[1];
    const void* Wq = d_in[2];
    const void* Wk = d_in[3];
    const void* Wv = d_in[4];
    const void* Wo = d_in[5];

    detect_kernel<<<1, 64, 0, stream>>>((const u32*)X, mask, flags);
    extract_start_kernel<<<S_LEN, 64, 0, stream>>>(mask, start, flags);
    cvt_bf16_kernel<<<1024, 256, 0, stream>>>(X, Xbf, (long)S_LEN * HID, flags);
    transpose_cvt_kernel<<<dim3(HID / 32, HID / 32), dim3(32, 8), 0, stream>>>(Wq, WqT, HID, HID, flags);
    transpose_cvt_kernel<<<dim3(DKV / 32, HID / 32), dim3(32, 8), 0, stream>>>(Wk, WkT, HID, DKV, flags);
    transpose_cvt_kernel<<<dim3(DKV / 32, HID / 32), dim3(32, 8), 0, stream>>>(Wv, WvT, HID, DKV, flags);
    transpose_cvt_kernel<<<dim3(HID / 32, HID / 32), dim3(32, 8), 0, stream>>>(Wo, WoT, HID, HID, flags);

    // fused QKV projection: BT = [WqT; WkT; WvT] = [3072][2048]
    gemm_qkv_kernel<<<dim3(24, HID / 128), 256, 0, stream>>>(Xbf, WqT, Qbf, Kbf, Vtb);

    attn_kernel<<<dim3(S_LEN / 16, NH), 256, 0, stream>>>(Qbf, Kbf, Vtb, Obf, start);

    gemm_bt_kernel<3><<<dim3(HID / 128, S_LEN / 128), 256, 0, stream>>>(Obf, WoT, d_out, S_LEN, HID, HID, 1.f);
}

// Round 5
// 196.608 us; speedup vs baseline: 1.3214x; 1.0400x over previous
//
#include <hip/hip_runtime.h>
#include <hip/hip_bf16.h>

// ---------- types ----------
typedef __attribute__((ext_vector_type(4))) float f32x4;
typedef __attribute__((ext_vector_type(8))) short bf16x8;   // 8 bf16 in 4 VGPRs
typedef unsigned short u16;
typedef unsigned int   u32;
typedef unsigned long long u64;

#define S_LEN 2048
#define HID   2048
#define NH    16
#define NKV   4
#define HD    128
#define DKV   512          // NKV*HD
#define QK_SCALE 0.08838834764831845f   // 1/sqrt(128)

__device__ __forceinline__ u16 f2bf(float x) {              // RNE f32 -> bf16 bits
    u32 u = __builtin_bit_cast(u32, x);
    u32 r = (u + 0x7fffu + ((u >> 16) & 1u)) >> 16;
    return (u16)r;
}
__device__ __forceinline__ float bf2f(u16 b) {
    u32 u = ((u32)b) << 16;
    return __builtin_bit_cast(float, u);
}
__device__ __forceinline__ void gload_lds16(const void* g, void* l) {
    __builtin_amdgcn_global_load_lds(
        (const __attribute__((address_space(1))) u32*)g,
        (__attribute__((address_space(3))) u32*)l, 16, 0, 0);
}

// ---------- dtype detection ----------
__global__ void detect_kernel(const u32* x, const unsigned char* mask, int* flags) {
    int lane = threadIdx.x;
    int big = 0, nz = 0;
    for (int i = lane; i < 256; i += 64) {
        u16 lo = (u16)(x[i] & 0xffffu);
        int e = (lo >> 7) & 0xff;
        big |= (e >= 0x83);
        nz  |= (lo != 0);
    }
    u64 bigb = __ballot(big);
    u64 nzb  = __ballot(nz);
    if (lane == 0) {
        flags[0] = (bigb != 0ull || nzb == 0ull) ? 1 : 0;   // 1 = f32 input
        flags[1] = (mask[2049] != 0) ? 1 : 4;               // mask elem width
    }
}

// ---------- per-row window start: start[i] = i+1 - count(true) ----------
__global__ void extract_start_kernel(const unsigned char* mask, int* start, const int* flags) {
    int i = blockIdx.x, lane = threadIdx.x;
    int w = flags[1];
    int cnt = 0;
    if (w == 1) {
        for (int j = lane; j < S_LEN; j += 64)
            cnt += (mask[(size_t)i * S_LEN + j] != 0);
    } else {
        const u32* m4 = (const u32*)mask;
        for (int j = lane; j < S_LEN; j += 64)
            cnt += (m4[(size_t)i * S_LEN + j] != 0);
    }
    #pragma unroll
    for (int off = 32; off; off >>= 1) cnt += __shfl_down(cnt, off);
    if (lane == 0) start[i] = i + 1 - cnt;
}

// ---------- convert (f32|bf16) -> bf16, contiguous ----------
__global__ void cvt_bf16_kernel(const void* in, u16* out, long n, const int* flags) {
    int isf32 = flags[0];
    long i = (long)blockIdx.x * blockDim.x + threadIdx.x;
    long stride = (long)gridDim.x * blockDim.x;
    if (isf32) {
        const float* p = (const float*)in;
        for (; i < n; i += stride) out[i] = f2bf(p[i]);
    } else {
        const u16* p = (const u16*)in;
        for (; i < n; i += stride) out[i] = p[i];
    }
}

// ---------- transpose + convert: W[K][N] -> WT[N][K] bf16 ----------
__global__ void transpose_cvt_kernel(const void* in, u16* out, int K, int N, const int* flags) {
    __shared__ float tile[32][33];
    int isf32 = flags[0];
    int n0 = blockIdx.x * 32, k0 = blockIdx.y * 32;
    for (int kk = threadIdx.y; kk < 32; kk += 8) {
        size_t idx = (size_t)(k0 + kk) * N + n0 + threadIdx.x;
        float v = isf32 ? ((const float*)in)[idx] : bf2f(((const u16*)in)[idx]);
        tile[kk][threadIdx.x] = v;
    }
    __syncthreads();
    for (int nn = threadIdx.y; nn < 32; nn += 8) {
        out[(size_t)(n0 + nn) * K + k0 + threadIdx.x] = f2bf(tile[threadIdx.x][nn]);
    }
}

// ================= fused QKV projection GEMM =================
__global__ __launch_bounds__(256) void gemm_qkv_kernel(
        const u16* __restrict__ A, const u16* __restrict__ BT,
        u16* __restrict__ Qo, u16* __restrict__ Ko, u16* __restrict__ Vto)
{
    __shared__ char smem[32768];
    const int tid = threadIdx.x;
    const int wave = tid >> 6, lane = tid & 63, g = lane >> 4, q = lane & 15;
    const int wr = wave >> 1, wc = wave & 1;
    const int m0 = blockIdx.y * 128, n0 = blockIdx.x * 128;
    const int K = HID;

    f32x4 acc[4][4];
    #pragma unroll
    for (int i = 0; i < 4; i++)
        #pragma unroll
        for (int j = 0; j < 4; j++) acc[i][j] = (f32x4){0.f, 0.f, 0.f, 0.f};

    for (int kt = 0; kt < (K >> 6); ++kt) {
        const int kbase = kt << 6;
        #pragma unroll
        for (int it = 0; it < 4; ++it) {
            int idx = it * 256 + tid;
            int row = idx >> 3, ch = idx & 7;
            int sch = ch ^ (row & 7);
            gload_lds16(A  + (size_t)(m0 + row) * K + kbase + sch * 8, smem + idx * 16);
            gload_lds16(BT + (size_t)(n0 + row) * K + kbase + sch * 8, smem + 16384 + idx * 16);
        }
        __syncthreads();
        #pragma unroll
        for (int kk = 0; kk < 2; ++kk) {
            bf16x8 af[4], bfr[4];
            #pragma unroll
            for (int i = 0; i < 4; i++) {
                int ra = wr * 64 + i * 16 + q;
                af[i]  = *(const bf16x8*)(smem + ra * 128 + (((kk * 4 + g) ^ (ra & 7)) * 16));
                int rb = wc * 64 + i * 16 + q;
                bfr[i] = *(const bf16x8*)(smem + 16384 + rb * 128 + (((kk * 4 + g) ^ (rb & 7)) * 16));
            }
            #pragma unroll
            for (int i = 0; i < 4; i++)
                #pragma unroll
                for (int j = 0; j < 4; j++)
                    acc[i][j] = __builtin_amdgcn_mfma_f32_16x16x32_bf16(af[i], bfr[j], acc[i][j], 0, 0, 0);
        }
        __syncthreads();
    }
    #pragma unroll
    for (int i = 0; i < 4; i++) {
        #pragma unroll
        for (int j = 0; j < 4; j++) {
            #pragma unroll
            for (int r = 0; r < 4; r++) {
                int m = m0 + wr * 64 + i * 16 + g * 4 + r;
                int n = n0 + wc * 64 + j * 16 + q;
                float v = acc[i][j][r];
                if (n0 < 2048)      Qo[(size_t)m * HID + n] = f2bf(v * QK_SCALE);
                else if (n0 < 2560) Ko[(size_t)m * DKV + (n - 2048)] = f2bf(v);
                else                Vto[(size_t)(n - 2560) * S_LEN + m] = f2bf(v);
            }
        }
    }
}

// ---------- GEMM: C = A[M][K]*B (BT[N][K]); MODE 0: bf16 out, MODE 3: f32 out ----------
template <int MODE>
__global__ __launch_bounds__(256) void gemm_bt_kernel(
        const u16* __restrict__ A, const u16* __restrict__ BT, void* __restrict__ Cv,
        int M, int N, int K, float scale)
{
    __shared__ char smem[32768];
    const int tid = threadIdx.x;
    const int wave = tid >> 6, lane = tid & 63, g = lane >> 4, q = lane & 15;
    const int wr = wave >> 1, wc = wave & 1;
    const int m0 = blockIdx.y * 128, n0 = blockIdx.x * 128;

    f32x4 acc[4][4];
    #pragma unroll
    for (int i = 0; i < 4; i++)
        #pragma unroll
        for (int j = 0; j < 4; j++) acc[i][j] = (f32x4){0.f, 0.f, 0.f, 0.f};

    for (int kt = 0; kt < (K >> 6); ++kt) {
        const int kbase = kt << 6;
        #pragma unroll
        for (int it = 0; it < 4; ++it) {
            int idx = it * 256 + tid;
            int row = idx >> 3, ch = idx & 7;
            int sch = ch ^ (row & 7);
            gload_lds16(A  + (size_t)(m0 + row) * K + kbase + sch * 8, smem + idx * 16);
            gload_lds16(BT + (size_t)(n0 + row) * K + kbase + sch * 8, smem + 16384 + idx * 16);
        }
        __syncthreads();
        #pragma unroll
        for (int kk = 0; kk < 2; ++kk) {
            bf16x8 af[4], bfr[4];
            #pragma unroll
            for (int i = 0; i < 4; i++) {
                int ra = wr * 64 + i * 16 + q;
                af[i]  = *(const bf16x8*)(smem + ra * 128 + (((kk * 4 + g) ^ (ra & 7)) * 16));
                int rb = wc * 64 + i * 16 + q;
                bfr[i] = *(const bf16x8*)(smem + 16384 + rb * 128 + (((kk * 4 + g) ^ (rb & 7)) * 16));
            }
            #pragma unroll
            for (int i = 0; i < 4; i++)
                #pragma unroll
                for (int j = 0; j < 4; j++)
                    acc[i][j] = __builtin_amdgcn_mfma_f32_16x16x32_bf16(af[i], bfr[j], acc[i][j], 0, 0, 0);
        }
        __syncthreads();
    }
    #pragma unroll
    for (int i = 0; i < 4; i++) {
        #pragma unroll
        for (int j = 0; j < 4; j++) {
            #pragma unroll
            for (int r = 0; r < 4; r++) {
                int m = m0 + wr * 64 + i * 16 + g * 4 + r;
                int n = n0 + wc * 64 + j * 16 + q;
                float v = acc[i][j][r] * scale;
                if (MODE == 3) ((float*)Cv)[(size_t)m * N + n] = v;
                else           ((u16*)Cv)[(size_t)m * N + n] = f2bf(v);
            }
        }
    }
}

// ================= adaptive-window flash attention =================
// Independent waves (16 q-rows each), 2-stage register-pipelined K/V loads,
// defer-max online softmax. grid (S/64, NH), block 256 = 4 waves.

__device__ __forceinline__ void attn_load(int j0, int g, int q, int hk,
        const u16* __restrict__ Kb, const u16* __restrict__ Vt,
        bf16x8 (&Kf)[2][4], bf16x8 (&Vf)[8])
{
    #pragma unroll
    for (int hf = 0; hf < 2; hf++) {
        int kj = j0 + hf * 16 + q; if (kj > S_LEN - 1) kj = S_LEN - 1;
        const u16* kp = Kb + (size_t)kj * DKV + hk * HD + g * 8;
        #pragma unroll
        for (int kk = 0; kk < 4; kk++) Kf[hf][kk] = *(const bf16x8*)(kp + kk * 32);
    }
    int jv = j0 + g * 8; if (jv > S_LEN - 8) jv = S_LEN - 8;
    #pragma unroll
    for (int t = 0; t < 8; t++)
        Vf[t] = *(const bf16x8*)(Vt + (size_t)(hk * HD + t * 16 + q) * S_LEN + jv);
}

__device__ __forceinline__ void attn_tile(
        int j0, int qrow, int startq, int g, int q, int hk,
        const bf16x8 (&Qf)[4],
        bf16x8 (&Kc)[2][4], bf16x8 (&Vc)[8],          // current tile (consumed)
        int jn, bool pf, bf16x8 (&Kn)[2][4], bf16x8 (&Vn)[8],  // next tile (prefetched)
        const u16* __restrict__ Kb, const u16* __restrict__ Vt,
        float& m, float& l, f32x4 (&o)[8], char* prow)
{
    // 1) issue next-tile loads first: they retire under this tile's compute
    if (pf) attn_load(jn, g, q, hk, Kb, Vt, Kn, Vn);

    // 2) S^T = K * Q^T (two independent 4-deep MFMA chains)
    f32x4 s0 = (f32x4){0.f, 0.f, 0.f, 0.f};
    f32x4 s1 = (f32x4){0.f, 0.f, 0.f, 0.f};
    #pragma unroll
    for (int kk = 0; kk < 4; kk++) {
        s0 = __builtin_amdgcn_mfma_f32_16x16x32_bf16(Kc[0][kk], Qf[kk], s0, 0, 0, 0);
        s1 = __builtin_amdgcn_mfma_f32_16x16x32_bf16(Kc[1][kk], Qf[kk], s1, 0, 0, 0);
    }

    // 3) mask + online softmax with defer-max
    float sv[8];
    float pmax = -INFINITY;
    #pragma unroll
    for (int r = 0; r < 4; r++) {
        int ja = j0 + g * 4 + r;
        float xa = (ja <= qrow && ja >= startq) ? s0[r] : -INFINITY;
        int jb = ja + 16;
        float xb = (jb <= qrow && jb >= startq) ? s1[r] : -INFINITY;
        sv[r] = xa; sv[4 + r] = xb;
        pmax = fmaxf(pmax, fmaxf(xa, xb));
    }
    pmax = fmaxf(pmax, __shfl_xor(pmax, 16));
    pmax = fmaxf(pmax, __shfl_xor(pmax, 32));

    bool defer = __all(pmax <= m + 8.f);      // wave-uniform
    float mnew = m;
    if (!defer) {
        mnew = fmaxf(m, pmax);
        float corr = (m == -INFINITY) ? 0.f : __expf(m - mnew);
        l *= corr;
        #pragma unroll
        for (int t = 0; t < 8; t++) {
            o[t][0] *= corr; o[t][1] *= corr; o[t][2] *= corr; o[t][3] *= corr;
        }
        m = mnew;
    }

    float ps = 0.f;
    u16 pb[8];
    #pragma unroll
    for (int t = 0; t < 8; t++) {
        float p = (sv[t] == -INFINITY) ? 0.f : __expf(sv[t] - mnew);
        ps += p;
        pb[t] = f2bf(p);
    }
    // 4) write P^T tile to wave-local LDS early (read waits overlap the sum shuffles)
    #pragma unroll
    for (int hf = 0; hf < 2; hf++) {
        u64 w = (u64)pb[hf * 4 + 0] | ((u64)pb[hf * 4 + 1] << 16) |
                ((u64)pb[hf * 4 + 2] << 32) | ((u64)pb[hf * 4 + 3] << 48);
        *(u64*)(prow + hf * 32 + g * 8) = w;
    }
    ps += __shfl_xor(ps, 16);
    ps += __shfl_xor(ps, 32);
    l += ps;

    // B-fragment read: row q base (prow) + g*16 bytes  [rounds 2-3 verified layout]
    bf16x8 Pf = *(const bf16x8*)(prow + g * 16);

    // 5) PV: O^T[d][q] += Vt[d][j] * P^T[j][q]  (8 independent accumulators)
    #pragma unroll
    for (int t = 0; t < 8; t++)
        o[t] = __builtin_amdgcn_mfma_f32_16x16x32_bf16(Vc[t], Pf, o[t], 0, 0, 0);
}

__global__ __launch_bounds__(256) void attn_kernel(
        const u16* __restrict__ Q, const u16* __restrict__ Kb,
        const u16* __restrict__ Vt, u16* __restrict__ O, const int* __restrict__ start)
{
    __shared__ char psm[4 * 1280];            // per-wave P^T tile: 16 rows x pitch 80B
    const int tid = threadIdx.x, wave = tid >> 6, lane = tid & 63;
    const int g = lane >> 4, q = lane & 15;
    const int h = blockIdx.y, hk = h >> 2;
    const int r0 = blockIdx.x * 64 + wave * 16;
    const int qrow = r0 + q;

    const u16* qp = Q + (size_t)qrow * HID + h * HD + g * 8;
    bf16x8 Qf[4];
    #pragma unroll
    for (int kk = 0; kk < 4; kk++) Qf[kk] = *(const bf16x8*)(qp + kk * 32);

    const int startq = start[qrow];
    int jlo = startq;
    #pragma unroll
    for (int off = 1; off < 16; off <<= 1) jlo = min(jlo, __shfl_xor(jlo, off));
    const int jend = r0 + 15;

    float m = -INFINITY, l = 0.f;
    f32x4 o[8];
    #pragma unroll
    for (int t = 0; t < 8; t++) o[t] = (f32x4){0.f, 0.f, 0.f, 0.f};

    char* prow = psm + wave * 1280 + q * 80;

    bf16x8 KA[2][4], VA[8], KB[2][4], VB[8];
    int j0 = jlo & ~31;
    attn_load(j0, g, q, hk, Kb, Vt, KA, VA);
    for (;;) {
        int j1 = j0 + 32; bool p1 = (j1 <= jend);
        attn_tile(j0, qrow, startq, g, q, hk, Qf, KA, VA, j1, p1, KB, VB, Kb, Vt, m, l, o, prow);
        if (!p1) break;
        int j2 = j1 + 32; bool p2 = (j2 <= jend);
        attn_tile(j1, qrow, startq, g, q, hk, Qf, KB, VB, j2, p2, KA, VA, Kb, Vt, m, l, o, prow);
        if (!p2) break;
        j0 = j2;
    }

    float inv = 1.0f / l;
    #pragma unroll
    for (int t = 0; t < 8; t++) {
        u64 w = (u64)f2bf(o[t][0] * inv) | ((u64)f2bf(o[t][1] * inv) << 16) |
                ((u64)f2bf(o[t][2] * inv) << 32) | ((u64)f2bf(o[t][3] * inv) << 48);
        *(u64*)(O + (size_t)qrow * HID + h * HD + t * 16 + g * 4) = w;
    }
}

// ---------- launch ----------
extern "C" void kernel_launch(void* const* d_in, const int* in_sizes, int n_in,
                              void* d_out, int out_size, void* d_ws, size_t ws_size,
                              hipStream_t stream)
{
    char* ws = (char*)d_ws;
    const size_t MB = 1024 * 1024;
    int* flags = (int*)(ws + 0);
    int* start = (int*)(ws + 1024);
    u16* Xbf = (u16*)(ws + 16384);
    u16* WqT = (u16*)(ws + 16384 + 8 * MB);    // [2048][2048]
    u16* WkT = (u16*)(ws + 16384 + 16 * MB);   // [512][2048]
    u16* WvT = (u16*)(ws + 16384 + 18 * MB);   // [512][2048]
    u16* WoT = (u16*)(ws + 16384 + 20 * MB);
    u16* Qbf = (u16*)(ws + 16384 + 28 * MB);
    u16* Kbf = (u16*)(ws + 16384 + 36 * MB);
    u16* Vtb = (u16*)(ws + 16384 + 38 * MB);
    u16* Obf = (u16*)(ws + 16384 + 40 * MB);

    const void* X  = d_in[0];
    const unsigned char* mask = (const unsigned char*)d_in[1];
    const void* Wq = d_in[2];
    const void* Wk = d_in[3];
    const void* Wv = d_in[4];
    const void* Wo = d_in[5];

    detect_kernel<<<1, 64, 0, stream>>>((const u32*)X, mask, flags);
    extract_start_kernel<<<S_LEN, 64, 0, stream>>>(mask, start, flags);
    cvt_bf16_kernel<<<1024, 256, 0, stream>>>(X, Xbf, (long)S_LEN * HID, flags);
    transpose_cvt_kernel<<<dim3(HID / 32, HID / 32), dim3(32, 8), 0, stream>>>(Wq, WqT, HID, HID, flags);
    transpose_cvt_kernel<<<dim3(DKV / 32, HID / 32), dim3(32, 8), 0, stream>>>(Wk, WkT, HID, DKV, flags);
    transpose_cvt_kernel<<<dim3(DKV / 32, HID / 32), dim3(32, 8), 0, stream>>>(Wv, WvT, HID, DKV, flags);
    transpose_cvt_kernel<<<dim3(HID / 32, HID / 32), dim3(32, 8), 0, stream>>>(Wo, WoT, HID, HID, flags);

    gemm_qkv_kernel<<<dim3(24, HID / 128), 256, 0, stream>>>(Xbf, WqT, Qbf, Kbf, Vtb);

    attn_kernel<<<dim3(S_LEN / 64, NH), 256, 0, stream>>>(Qbf, Kbf, Vtb, Obf, start);

    gemm_bt_kernel<3><<<dim3(HID / 128, S_LEN / 128), 256, 0, stream>>>(Obf, WoT, d_out, S_LEN, HID, HID, 1.f);
}

// Round 6
// 166.398 us; speedup vs baseline: 1.5613x; 1.1816x over previous
//
#include <hip/hip_runtime.h>
#include <hip/hip_bf16.h>

// ---------- types ----------
typedef __attribute__((ext_vector_type(4)))  float f32x4;
typedef __attribute__((ext_vector_type(16))) float f32x16;
typedef __attribute__((ext_vector_type(8)))  short bf16x8;   // 8 bf16 in 4 VGPRs
typedef unsigned short u16;
typedef unsigned int   u32;
typedef unsigned long long u64;
typedef __attribute__((ext_vector_type(2))) u32 u32x2;
typedef __attribute__((ext_vector_type(4))) u32 u32x4;

#define S_LEN 2048
#define HID   2048
#define NH    16
#define NKV   4
#define HD    128
#define DKV   512          // NKV*HD
#define QK_SCALE 0.08838834764831845f   // 1/sqrt(128)

__device__ __forceinline__ u16 f2bf(float x) {              // RNE f32 -> bf16 bits
    u32 u = __builtin_bit_cast(u32, x);
    u32 r = (u + 0x7fffu + ((u >> 16) & 1u)) >> 16;
    return (u16)r;
}
__device__ __forceinline__ float bf2f(u16 b) {
    u32 u = ((u32)b) << 16;
    return __builtin_bit_cast(float, u);
}
__device__ __forceinline__ void gload_lds16(const void* g, void* l) {
    __builtin_amdgcn_global_load_lds(
        (const __attribute__((address_space(1))) u32*)g,
        (__attribute__((address_space(3))) u32*)l, 16, 0, 0);
}

// lane pair (L, L^32) exchange: x0/x1 per v_permlane32_swap semantics
// x0 = lane<32 ? a : b[lane-32];  x1 = lane<32 ? a[lane+32] : b
__device__ __forceinline__ void plswap(u32 a, u32 b, u32& x0, u32& x1) {
#if __has_builtin(__builtin_amdgcn_permlane32_swap)
    u32x2 r = __builtin_amdgcn_permlane32_swap(a, b, false, false);
    x0 = r[0]; x1 = r[1];
#else
    u32 oa = (u32)__shfl_xor((int)a, 32);
    u32 ob = (u32)__shfl_xor((int)b, 32);
    int hi = (threadIdx.x & 63) >> 5;
    x0 = hi ? ob : a;
    x1 = hi ? b : oa;
#endif
}
__device__ __forceinline__ float pairmax32(float v) {
    u32 x0, x1; plswap(__builtin_bit_cast(u32, v), __builtin_bit_cast(u32, v), x0, x1);
    return fmaxf(__builtin_bit_cast(float, x0), __builtin_bit_cast(float, x1));
}
__device__ __forceinline__ float pairsum32(float v) {
    u32 x0, x1; plswap(__builtin_bit_cast(u32, v), __builtin_bit_cast(u32, v), x0, x1);
    return __builtin_bit_cast(float, x0) + __builtin_bit_cast(float, x1);
}

// ---------- dtype detection ----------
__global__ void detect_kernel(const u32* x, const unsigned char* mask, int* flags) {
    int lane = threadIdx.x;
    int big = 0, nz = 0;
    for (int i = lane; i < 256; i += 64) {
        u16 lo = (u16)(x[i] & 0xffffu);
        int e = (lo >> 7) & 0xff;
        big |= (e >= 0x83);
        nz  |= (lo != 0);
    }
    u64 bigb = __ballot(big);
    u64 nzb  = __ballot(nz);
    if (lane == 0) {
        flags[0] = (bigb != 0ull || nzb == 0ull) ? 1 : 0;   // 1 = f32 input
        flags[1] = (mask[2049] != 0) ? 1 : 4;               // mask elem width
    }
}

// ---------- per-row window start: start[i] = i+1 - count(true) ----------
__global__ void extract_start_kernel(const unsigned char* mask, int* start, const int* flags) {
    int i = blockIdx.x, lane = threadIdx.x;
    int w = flags[1];
    int cnt = 0;
    if (w == 1) {
        for (int j = lane; j < S_LEN; j += 64)
            cnt += (mask[(size_t)i * S_LEN + j] != 0);
    } else {
        const u32* m4 = (const u32*)mask;
        for (int j = lane; j < S_LEN; j += 64)
            cnt += (m4[(size_t)i * S_LEN + j] != 0);
    }
    #pragma unroll
    for (int off = 32; off; off >>= 1) cnt += __shfl_down(cnt, off);
    if (lane == 0) start[i] = i + 1 - cnt;
}

// ---------- convert (f32|bf16) -> bf16, contiguous ----------
__global__ void cvt_bf16_kernel(const void* in, u16* out, long n, const int* flags) {
    int isf32 = flags[0];
    long i = (long)blockIdx.x * blockDim.x + threadIdx.x;
    long stride = (long)gridDim.x * blockDim.x;
    if (isf32) {
        const float* p = (const float*)in;
        for (; i < n; i += stride) out[i] = f2bf(p[i]);
    } else {
        const u16* p = (const u16*)in;
        for (; i < n; i += stride) out[i] = p[i];
    }
}

// ---------- transpose + convert: W[K][N] -> WT[N][K] bf16 ----------
__global__ void transpose_cvt_kernel(const void* in, u16* out, int K, int N, const int* flags) {
    __shared__ float tile[32][33];
    int isf32 = flags[0];
    int n0 = blockIdx.x * 32, k0 = blockIdx.y * 32;
    for (int kk = threadIdx.y; kk < 32; kk += 8) {
        size_t idx = (size_t)(k0 + kk) * N + n0 + threadIdx.x;
        float v = isf32 ? ((const float*)in)[idx] : bf2f(((const u16*)in)[idx]);
        tile[kk][threadIdx.x] = v;
    }
    __syncthreads();
    for (int nn = threadIdx.y; nn < 32; nn += 8) {
        out[(size_t)(n0 + nn) * K + k0 + threadIdx.x] = f2bf(tile[threadIdx.x][nn]);
    }
}

// ================= fused QKV projection GEMM =================
__global__ __launch_bounds__(256) void gemm_qkv_kernel(
        const u16* __restrict__ A, const u16* __restrict__ BT,
        u16* __restrict__ Qo, u16* __restrict__ Ko, u16* __restrict__ Vto)
{
    __shared__ char smem[32768];
    const int tid = threadIdx.x;
    const int wave = tid >> 6, lane = tid & 63, g = lane >> 4, q = lane & 15;
    const int wr = wave >> 1, wc = wave & 1;
    const int m0 = blockIdx.y * 128, n0 = blockIdx.x * 128;
    const int K = HID;

    f32x4 acc[4][4];
    #pragma unroll
    for (int i = 0; i < 4; i++)
        #pragma unroll
        for (int j = 0; j < 4; j++) acc[i][j] = (f32x4){0.f, 0.f, 0.f, 0.f};

    for (int kt = 0; kt < (K >> 6); ++kt) {
        const int kbase = kt << 6;
        #pragma unroll
        for (int it = 0; it < 4; ++it) {
            int idx = it * 256 + tid;
            int row = idx >> 3, ch = idx & 7;
            int sch = ch ^ (row & 7);
            gload_lds16(A  + (size_t)(m0 + row) * K + kbase + sch * 8, smem + idx * 16);
            gload_lds16(BT + (size_t)(n0 + row) * K + kbase + sch * 8, smem + 16384 + idx * 16);
        }
        __syncthreads();
        #pragma unroll
        for (int kk = 0; kk < 2; ++kk) {
            bf16x8 af[4], bfr[4];
            #pragma unroll
            for (int i = 0; i < 4; i++) {
                int ra = wr * 64 + i * 16 + q;
                af[i]  = *(const bf16x8*)(smem + ra * 128 + (((kk * 4 + g) ^ (ra & 7)) * 16));
                int rb = wc * 64 + i * 16 + q;
                bfr[i] = *(const bf16x8*)(smem + 16384 + rb * 128 + (((kk * 4 + g) ^ (rb & 7)) * 16));
            }
            #pragma unroll
            for (int i = 0; i < 4; i++)
                #pragma unroll
                for (int j = 0; j < 4; j++)
                    acc[i][j] = __builtin_amdgcn_mfma_f32_16x16x32_bf16(af[i], bfr[j], acc[i][j], 0, 0, 0);
        }
        __syncthreads();
    }
    #pragma unroll
    for (int i = 0; i < 4; i++) {
        #pragma unroll
        for (int j = 0; j < 4; j++) {
            #pragma unroll
            for (int r = 0; r < 4; r++) {
                int m = m0 + wr * 64 + i * 16 + g * 4 + r;
                int n = n0 + wc * 64 + j * 16 + q;
                float v = acc[i][j][r];
                if (n0 < 2048)      Qo[(size_t)m * HID + n] = f2bf(v * QK_SCALE);
                else if (n0 < 2560) Ko[(size_t)m * DKV + (n - 2048)] = f2bf(v);
                else                Vto[(size_t)(n - 2560) * S_LEN + m] = f2bf(v);
            }
        }
    }
}

// ---------- GEMM: C = A[M][K]*B (BT[N][K]); MODE 0: bf16 out, MODE 3: f32 out ----------
template <int MODE>
__global__ __launch_bounds__(256) void gemm_bt_kernel(
        const u16* __restrict__ A, const u16* __restrict__ BT, void* __restrict__ Cv,
        int M, int N, int K, float scale)
{
    __shared__ char smem[32768];
    const int tid = threadIdx.x;
    const int wave = tid >> 6, lane = tid & 63, g = lane >> 4, q = lane & 15;
    const int wr = wave >> 1, wc = wave & 1;
    const int m0 = blockIdx.y * 128, n0 = blockIdx.x * 128;

    f32x4 acc[4][4];
    #pragma unroll
    for (int i = 0; i < 4; i++)
        #pragma unroll
        for (int j = 0; j < 4; j++) acc[i][j] = (f32x4){0.f, 0.f, 0.f, 0.f};

    for (int kt = 0; kt < (K >> 6); ++kt) {
        const int kbase = kt << 6;
        #pragma unroll
        for (int it = 0; it < 4; ++it) {
            int idx = it * 256 + tid;
            int row = idx >> 3, ch = idx & 7;
            int sch = ch ^ (row & 7);
            gload_lds16(A  + (size_t)(m0 + row) * K + kbase + sch * 8, smem + idx * 16);
            gload_lds16(BT + (size_t)(n0 + row) * K + kbase + sch * 8, smem + 16384 + idx * 16);
        }
        __syncthreads();
        #pragma unroll
        for (int kk = 0; kk < 2; ++kk) {
            bf16x8 af[4], bfr[4];
            #pragma unroll
            for (int i = 0; i < 4; i++) {
                int ra = wr * 64 + i * 16 + q;
                af[i]  = *(const bf16x8*)(smem + ra * 128 + (((kk * 4 + g) ^ (ra & 7)) * 16));
                int rb = wc * 64 + i * 16 + q;
                bfr[i] = *(const bf16x8*)(smem + 16384 + rb * 128 + (((kk * 4 + g) ^ (rb & 7)) * 16));
            }
            #pragma unroll
            for (int i = 0; i < 4; i++)
                #pragma unroll
                for (int j = 0; j < 4; j++)
                    acc[i][j] = __builtin_amdgcn_mfma_f32_16x16x32_bf16(af[i], bfr[j], acc[i][j], 0, 0, 0);
        }
        __syncthreads();
    }
    #pragma unroll
    for (int i = 0; i < 4; i++) {
        #pragma unroll
        for (int j = 0; j < 4; j++) {
            #pragma unroll
            for (int r = 0; r < 4; r++) {
                int m = m0 + wr * 64 + i * 16 + g * 4 + r;
                int n = n0 + wc * 64 + j * 16 + q;
                float v = acc[i][j][r] * scale;
                if (MODE == 3) ((float*)Cv)[(size_t)m * N + n] = v;
                else           ((u16*)Cv)[(size_t)m * N + n] = f2bf(v);
            }
        }
    }
}

// ================= adaptive-window flash attention, 32x32 swapped-operand =================
// Wave owns 32 q-rows; S^T = K * Q^T via mfma_f32_32x32x16 (D: col=q=lane&31,
// row=key=(r&3)+8*(r>>2)+4*hi). Softmax fully in-register: in-lane 16-max/sum +
// one permlane32_swap. P->B-frag redistribution via permlane pairs (w_j, w_{j+2}).
// O^T[d][q] accumulated in 4 x f32x16; V^T read direct from global (L2-hot).
// grid (S/128, NH), block 256 = 4 waves, zero LDS.
__global__ __launch_bounds__(256, 1) void attn_kernel(
        const u16* __restrict__ Q, const u16* __restrict__ Kb,
        const u16* __restrict__ Vt, u16* __restrict__ O, const int* __restrict__ start)
{
    const int tid = threadIdx.x, wave = tid >> 6, lane = tid & 63;
    const int q = lane & 31, hi = lane >> 5;
    const int h = blockIdx.y, hk = h >> 2;
    const int r0 = blockIdx.x * 128 + wave * 32;
    const int qrow = r0 + q;

    // Q B-frags: lane holds Q[qrow][kc*16 + hi*8 + e]
    const u16* qp = Q + (size_t)qrow * HID + h * HD + hi * 8;
    bf16x8 Qf[8];
    #pragma unroll
    for (int kc = 0; kc < 8; kc++) Qf[kc] = *(const bf16x8*)(qp + kc * 16);

    const int startq = start[qrow];
    int jlo = startq;
    #pragma unroll
    for (int off = 1; off < 32; off <<= 1) jlo = min(jlo, __shfl_xor(jlo, off));
    const int jend = r0 + 31;

    float m = -INFINITY, l = 0.f;
    f32x16 o[4];
    #pragma unroll
    for (int dt = 0; dt < 4; dt++) o[dt] = (f32x16){};

    for (int j0 = (jlo & ~31); j0 <= jend; j0 += 32) {
        // ---- K A-frags: K[j0+q][hk*128 + kc*16 + hi*8] (all issue first) ----
        const u16* kp = Kb + (size_t)(j0 + q) * DKV + hk * HD + hi * 8;
        bf16x8 Kf[8];
        #pragma unroll
        for (int kc = 0; kc < 8; kc++) Kf[kc] = *(const bf16x8*)(kp + kc * 16);
        // ---- V A-frags: Vt[hk*128 + dt*32 + q][j0 + c*16 + hi*8] (retire under QK/softmax) ----
        const u16* vp = Vt + (size_t)(hk * HD + q) * S_LEN + j0 + hi * 8;
        bf16x8 Vf[8];
        #pragma unroll
        for (int dt = 0; dt < 4; dt++)
            #pragma unroll
            for (int c = 0; c < 2; c++)
                Vf[dt * 2 + c] = *(const bf16x8*)(vp + (size_t)dt * 32 * S_LEN + c * 16);

        // ---- S^T = K * Q^T : 32x32, accumulate over 8 d-chunks ----
        f32x16 s = (f32x16){};
        #pragma unroll
        for (int kc = 0; kc < 8; kc++)
            s = __builtin_amdgcn_mfma_f32_32x32x16_bf16(Kf[kc], Qf[kc], s, 0, 0, 0);

        // ---- mask + in-lane max (16 keys/lane) + pair-swap ----
        float sv[16];
        float pmax = -INFINITY;
        #pragma unroll
        for (int r = 0; r < 16; r++) {
            int j = j0 + (r & 3) + 8 * (r >> 2) + 4 * hi;
            float x = (j <= qrow && j >= startq) ? s[r] : -INFINITY;
            sv[r] = x;
            pmax = fmaxf(pmax, x);
        }
        pmax = pairmax32(pmax);

        bool defer = __all(pmax <= m + 8.f);      // wave-uniform
        float mnew = m;
        if (!defer) {
            mnew = fmaxf(m, pmax);
            float corr = (m == -INFINITY) ? 0.f : __expf(m - mnew);
            l *= corr;
            #pragma unroll
            for (int dt = 0; dt < 4; dt++)
                #pragma unroll
                for (int r = 0; r < 16; r++) o[dt][r] *= corr;
            m = mnew;
        }

        // ---- exp + sum + bf16 pack ----
        float ps = 0.f;
        u16 pb[16];
        #pragma unroll
        for (int r = 0; r < 16; r++) {
            float p = (sv[r] == -INFINITY) ? 0.f : __expf(sv[r] - mnew);
            ps += p;
            pb[r] = f2bf(p);
        }
        l += pairsum32(ps);

        // ---- P^T B-frags via permlane pair-exchange ----
        u32 w[8];
        #pragma unroll
        for (int i = 0; i < 8; i++) w[i] = (u32)pb[2 * i] | ((u32)pb[2 * i + 1] << 16);
        u32 x0, x1, y0, y1;
        plswap(w[0], w[2], x0, x1); plswap(w[1], w[3], y0, y1);
        u32x4 c0w = {x0, y0, x1, y1};
        bf16x8 P0 = __builtin_bit_cast(bf16x8, c0w);
        plswap(w[4], w[6], x0, x1); plswap(w[5], w[7], y0, y1);
        u32x4 c1w = {x0, y0, x1, y1};
        bf16x8 P1 = __builtin_bit_cast(bf16x8, c1w);

        // ---- PV: O^T[d][q] += V^T[d][key] * P^T[key][q] ----
        #pragma unroll
        for (int dt = 0; dt < 4; dt++) {
            o[dt] = __builtin_amdgcn_mfma_f32_32x32x16_bf16(Vf[dt * 2 + 0], P0, o[dt], 0, 0, 0);
            o[dt] = __builtin_amdgcn_mfma_f32_32x32x16_bf16(Vf[dt * 2 + 1], P1, o[dt], 0, 0, 0);
        }
    }

    // ---- epilogue: O[qrow][h*128 + dt*32 + 8*(rb/4) + 4*hi + e] ----
    float inv = 1.0f / l;
    u16* op = O + (size_t)qrow * HID + h * HD + 4 * hi;
    #pragma unroll
    for (int dt = 0; dt < 4; dt++) {
        #pragma unroll
        for (int rb = 0; rb < 16; rb += 4) {
            u64 wd = (u64)f2bf(o[dt][rb + 0] * inv) |
                     ((u64)f2bf(o[dt][rb + 1] * inv) << 16) |
                     ((u64)f2bf(o[dt][rb + 2] * inv) << 32) |
                     ((u64)f2bf(o[dt][rb + 3] * inv) << 48);
            *(u64*)(op + dt * 32 + 2 * rb) = wd;   // 8*(rb/4) = 2*rb
        }
    }
}

// ---------- launch ----------
extern "C" void kernel_launch(void* const* d_in, const int* in_sizes, int n_in,
                              void* d_out, int out_size, void* d_ws, size_t ws_size,
                              hipStream_t stream)
{
    char* ws = (char*)d_ws;
    const size_t MB = 1024 * 1024;
    int* flags = (int*)(ws + 0);
    int* start = (int*)(ws + 1024);
    u16* Xbf = (u16*)(ws + 16384);
    u16* WqT = (u16*)(ws + 16384 + 8 * MB);    // [2048][2048]
    u16* WkT = (u16*)(ws + 16384 + 16 * MB);   // [512][2048]
    u16* WvT = (u16*)(ws + 16384 + 18 * MB);   // [512][2048]
    u16* WoT = (u16*)(ws + 16384 + 20 * MB);
    u16* Qbf = (u16*)(ws + 16384 + 28 * MB);
    u16* Kbf = (u16*)(ws + 16384 + 36 * MB);
    u16* Vtb = (u16*)(ws + 16384 + 38 * MB);
    u16* Obf = (u16*)(ws + 16384 + 40 * MB);

    const void* X  = d_in[0];
    const unsigned char* mask = (const unsigned char*)d_in[1];
    const void* Wq = d_in[2];
    const void* Wk = d_in[3];
    const void* Wv = d_in[4];
    const void* Wo = d_in[5];

    detect_kernel<<<1, 64, 0, stream>>>((const u32*)X, mask, flags);
    extract_start_kernel<<<S_LEN, 64, 0, stream>>>(mask, start, flags);
    cvt_bf16_kernel<<<1024, 256, 0, stream>>>(X, Xbf, (long)S_LEN * HID, flags);
    transpose_cvt_kernel<<<dim3(HID / 32, HID / 32), dim3(32, 8), 0, stream>>>(Wq, WqT, HID, HID, flags);
    transpose_cvt_kernel<<<dim3(DKV / 32, HID / 32), dim3(32, 8), 0, stream>>>(Wk, WkT, HID, DKV, flags);
    transpose_cvt_kernel<<<dim3(DKV / 32, HID / 32), dim3(32, 8), 0, stream>>>(Wv, WvT, HID, DKV, flags);
    transpose_cvt_kernel<<<dim3(HID / 32, HID / 32), dim3(32, 8), 0, stream>>>(Wo, WoT, HID, HID, flags);

    gemm_qkv_kernel<<<dim3(24, HID / 128), 256, 0, stream>>>(Xbf, WqT, Qbf, Kbf, Vtb);

    attn_kernel<<<dim3(S_LEN / 128, NH), 256, 0, stream>>>(Qbf, Kbf, Vtb, Obf, start);

    gemm_bt_kernel<3><<<dim3(HID / 128, S_LEN / 128), 256, 0, stream>>>(Obf, WoT, d_out, S_LEN, HID, HID, 1.f);
}

// Round 7
// 148.041 us; speedup vs baseline: 1.7549x; 1.1240x over previous
//
#include <hip/hip_runtime.h>
#include <hip/hip_bf16.h>

// ---------- types ----------
typedef __attribute__((ext_vector_type(4)))  float f32x4;
typedef __attribute__((ext_vector_type(16))) float f32x16;
typedef __attribute__((ext_vector_type(8)))  short bf16x8;   // 8 bf16 in 4 VGPRs
typedef unsigned short u16;
typedef unsigned int   u32;
typedef unsigned long long u64;
typedef __attribute__((ext_vector_type(2))) u32 u32x2;
typedef __attribute__((ext_vector_type(4))) u32 u32x4;

#define S_LEN 2048
#define HID   2048
#define NH    16
#define NKV   4
#define HD    128
#define DKV   512          // NKV*HD
#define QK_SCALE 0.08838834764831845f   // 1/sqrt(128)

__device__ __forceinline__ u16 f2bf(float x) {              // RNE f32 -> bf16 bits
    u32 u = __builtin_bit_cast(u32, x);
    u32 r = (u + 0x7fffu + ((u >> 16) & 1u)) >> 16;
    return (u16)r;
}
__device__ __forceinline__ float bf2f(u16 b) {
    u32 u = ((u32)b) << 16;
    return __builtin_bit_cast(float, u);
}
__device__ __forceinline__ void gload_lds16(const void* g, void* l) {
    __builtin_amdgcn_global_load_lds(
        (const __attribute__((address_space(1))) u32*)g,
        (__attribute__((address_space(3))) u32*)l, 16, 0, 0);
}

// lane pair (L, L^32) exchange: x0/x1 per v_permlane32_swap semantics
__device__ __forceinline__ void plswap(u32 a, u32 b, u32& x0, u32& x1) {
#if __has_builtin(__builtin_amdgcn_permlane32_swap)
    u32x2 r = __builtin_amdgcn_permlane32_swap(a, b, false, false);
    x0 = r[0]; x1 = r[1];
#else
    u32 oa = (u32)__shfl_xor((int)a, 32);
    u32 ob = (u32)__shfl_xor((int)b, 32);
    int hi = (threadIdx.x & 63) >> 5;
    x0 = hi ? ob : a;
    x1 = hi ? b : oa;
#endif
}
__device__ __forceinline__ float pairmax32(float v) {
    u32 x0, x1; plswap(__builtin_bit_cast(u32, v), __builtin_bit_cast(u32, v), x0, x1);
    return fmaxf(__builtin_bit_cast(float, x0), __builtin_bit_cast(float, x1));
}
__device__ __forceinline__ float pairsum32(float v) {
    u32 x0, x1; plswap(__builtin_bit_cast(u32, v), __builtin_bit_cast(u32, v), x0, x1);
    return __builtin_bit_cast(float, x0) + __builtin_bit_cast(float, x1);
}

// ---------- dtype detection ----------
__global__ void detect_kernel(const u32* x, const unsigned char* mask, int* flags) {
    int lane = threadIdx.x;
    int big = 0, nz = 0;
    for (int i = lane; i < 256; i += 64) {
        u16 lo = (u16)(x[i] & 0xffffu);
        int e = (lo >> 7) & 0xff;
        big |= (e >= 0x83);
        nz  |= (lo != 0);
    }
    u64 bigb = __ballot(big);
    u64 nzb  = __ballot(nz);
    if (lane == 0) {
        flags[0] = (bigb != 0ull || nzb == 0ull) ? 1 : 0;   // 1 = f32 input
        flags[1] = (mask[2049] != 0) ? 1 : 4;               // mask elem width
    }
}

// ---------- per-row window start: start[i] = i+1 - count(true) ----------
__global__ void extract_start_kernel(const unsigned char* mask, int* start, const int* flags) {
    int i = blockIdx.x, lane = threadIdx.x;
    int w = flags[1];
    int cnt = 0;
    if (w == 1) {
        for (int j = lane; j < S_LEN; j += 64)
            cnt += (mask[(size_t)i * S_LEN + j] != 0);
    } else {
        const u32* m4 = (const u32*)mask;
        for (int j = lane; j < S_LEN; j += 64)
            cnt += (m4[(size_t)i * S_LEN + j] != 0);
    }
    #pragma unroll
    for (int off = 32; off; off >>= 1) cnt += __shfl_down(cnt, off);
    if (lane == 0) start[i] = i + 1 - cnt;
}

// ---------- convert (f32|bf16) -> bf16, contiguous ----------
__global__ void cvt_bf16_kernel(const void* in, u16* out, long n, const int* flags) {
    int isf32 = flags[0];
    long i = (long)blockIdx.x * blockDim.x + threadIdx.x;
    long stride = (long)gridDim.x * blockDim.x;
    if (isf32) {
        const float* p = (const float*)in;
        for (; i < n; i += stride) out[i] = f2bf(p[i]);
    } else {
        const u16* p = (const u16*)in;
        for (; i < n; i += stride) out[i] = p[i];
    }
}

// ---------- transpose + convert: W[K][N] -> WT[N][K] bf16 ----------
__global__ void transpose_cvt_kernel(const void* in, u16* out, int K, int N, const int* flags) {
    __shared__ float tile[32][33];
    int isf32 = flags[0];
    int n0 = blockIdx.x * 32, k0 = blockIdx.y * 32;
    for (int kk = threadIdx.y; kk < 32; kk += 8) {
        size_t idx = (size_t)(k0 + kk) * N + n0 + threadIdx.x;
        float v = isf32 ? ((const float*)in)[idx] : bf2f(((const u16*)in)[idx]);
        tile[kk][threadIdx.x] = v;
    }
    __syncthreads();
    for (int nn = threadIdx.y; nn < 32; nn += 8) {
        out[(size_t)(n0 + nn) * K + k0 + threadIdx.x] = f2bf(tile[threadIdx.x][nn]);
    }
}

// ================= fused QKV projection GEMM (2-phase double-buffered) =================
__global__ __launch_bounds__(256) void gemm_qkv_kernel(
        const u16* __restrict__ A, const u16* __restrict__ BT,
        u16* __restrict__ Qo, u16* __restrict__ Ko, u16* __restrict__ Vto)
{
    __shared__ char smem[65536];   // A: buf*16384 ; B: 32768 + buf*16384
    const int tid = threadIdx.x;
    const int wave = tid >> 6, lane = tid & 63, g = lane >> 4, q = lane & 15;
    const int wr = wave >> 1, wc = wave & 1;
    const int m0 = blockIdx.y * 128, n0 = blockIdx.x * 128;
    const int K = HID;

    f32x4 acc[4][4];
    #pragma unroll
    for (int i = 0; i < 4; i++)
        #pragma unroll
        for (int j = 0; j < 4; j++) acc[i][j] = (f32x4){0.f, 0.f, 0.f, 0.f};

    auto stage = [&](int kt, int b) {
        const int kbase = kt << 6;
        #pragma unroll
        for (int it = 0; it < 4; ++it) {
            int idx = it * 256 + tid;
            int row = idx >> 3, ch = idx & 7;
            int sch = ch ^ (row & 7);
            gload_lds16(A  + (size_t)(m0 + row) * K + kbase + sch * 8, smem + b * 16384 + idx * 16);
            gload_lds16(BT + (size_t)(n0 + row) * K + kbase + sch * 8, smem + 32768 + b * 16384 + idx * 16);
        }
    };

    const int KT = K >> 6;
    stage(0, 0);
    __syncthreads();
    int cur = 0;
    for (int kt = 0; kt < KT; ++kt) {
        if (kt + 1 < KT) stage(kt + 1, cur ^ 1);   // issue next-tile loads: retire under compute
        const char* sa = smem + cur * 16384;
        const char* sb = smem + 32768 + cur * 16384;
        #pragma unroll
        for (int kk = 0; kk < 2; ++kk) {
            bf16x8 af[4], bfr[4];
            #pragma unroll
            for (int i = 0; i < 4; i++) {
                int ra = wr * 64 + i * 16 + q;
                af[i]  = *(const bf16x8*)(sa + ra * 128 + (((kk * 4 + g) ^ (ra & 7)) * 16));
                int rb = wc * 64 + i * 16 + q;
                bfr[i] = *(const bf16x8*)(sb + rb * 128 + (((kk * 4 + g) ^ (rb & 7)) * 16));
            }
            #pragma unroll
            for (int i = 0; i < 4; i++)
                #pragma unroll
                for (int j = 0; j < 4; j++)
                    acc[i][j] = __builtin_amdgcn_mfma_f32_16x16x32_bf16(af[i], bfr[j], acc[i][j], 0, 0, 0);
        }
        __syncthreads();           // vmcnt(0)+lgkmcnt(0) drain: next buffer ready
        cur ^= 1;
    }
    #pragma unroll
    for (int i = 0; i < 4; i++) {
        #pragma unroll
        for (int j = 0; j < 4; j++) {
            #pragma unroll
            for (int r = 0; r < 4; r++) {
                int m = m0 + wr * 64 + i * 16 + g * 4 + r;
                int n = n0 + wc * 64 + j * 16 + q;
                float v = acc[i][j][r];
                if (n0 < 2048)      Qo[(size_t)m * HID + n] = f2bf(v * QK_SCALE);
                else if (n0 < 2560) Ko[(size_t)m * DKV + (n - 2048)] = f2bf(v);
                else                Vto[(size_t)(n - 2560) * S_LEN + m] = f2bf(v);
            }
        }
    }
}

// ---------- GEMM: C = A[M][K]*B (BT[N][K]), 2-phase double-buffered ----------
//  MODE 0: bf16 out   MODE 3: f32 out
template <int MODE>
__global__ __launch_bounds__(256) void gemm_bt_kernel(
        const u16* __restrict__ A, const u16* __restrict__ BT, void* __restrict__ Cv,
        int M, int N, int K, float scale)
{
    __shared__ char smem[65536];   // A: buf*16384 ; B: 32768 + buf*16384
    const int tid = threadIdx.x;
    const int wave = tid >> 6, lane = tid & 63, g = lane >> 4, q = lane & 15;
    const int wr = wave >> 1, wc = wave & 1;
    const int m0 = blockIdx.y * 128, n0 = blockIdx.x * 128;

    f32x4 acc[4][4];
    #pragma unroll
    for (int i = 0; i < 4; i++)
        #pragma unroll
        for (int j = 0; j < 4; j++) acc[i][j] = (f32x4){0.f, 0.f, 0.f, 0.f};

    auto stage = [&](int kt, int b) {
        const int kbase = kt << 6;
        #pragma unroll
        for (int it = 0; it < 4; ++it) {
            int idx = it * 256 + tid;
            int row = idx >> 3, ch = idx & 7;
            int sch = ch ^ (row & 7);
            gload_lds16(A  + (size_t)(m0 + row) * K + kbase + sch * 8, smem + b * 16384 + idx * 16);
            gload_lds16(BT + (size_t)(n0 + row) * K + kbase + sch * 8, smem + 32768 + b * 16384 + idx * 16);
        }
    };

    const int KT = K >> 6;
    stage(0, 0);
    __syncthreads();
    int cur = 0;
    for (int kt = 0; kt < KT; ++kt) {
        if (kt + 1 < KT) stage(kt + 1, cur ^ 1);
        const char* sa = smem + cur * 16384;
        const char* sb = smem + 32768 + cur * 16384;
        #pragma unroll
        for (int kk = 0; kk < 2; ++kk) {
            bf16x8 af[4], bfr[4];
            #pragma unroll
            for (int i = 0; i < 4; i++) {
                int ra = wr * 64 + i * 16 + q;
                af[i]  = *(const bf16x8*)(sa + ra * 128 + (((kk * 4 + g) ^ (ra & 7)) * 16));
                int rb = wc * 64 + i * 16 + q;
                bfr[i] = *(const bf16x8*)(sb + rb * 128 + (((kk * 4 + g) ^ (rb & 7)) * 16));
            }
            #pragma unroll
            for (int i = 0; i < 4; i++)
                #pragma unroll
                for (int j = 0; j < 4; j++)
                    acc[i][j] = __builtin_amdgcn_mfma_f32_16x16x32_bf16(af[i], bfr[j], acc[i][j], 0, 0, 0);
        }
        __syncthreads();
        cur ^= 1;
    }
    #pragma unroll
    for (int i = 0; i < 4; i++) {
        #pragma unroll
        for (int j = 0; j < 4; j++) {
            #pragma unroll
            for (int r = 0; r < 4; r++) {
                int m = m0 + wr * 64 + i * 16 + g * 4 + r;
                int n = n0 + wc * 64 + j * 16 + q;
                float v = acc[i][j][r] * scale;
                if (MODE == 3) ((float*)Cv)[(size_t)m * N + n] = v;
                else           ((u16*)Cv)[(size_t)m * N + n] = f2bf(v);
            }
        }
    }
}

// ================= adaptive-window flash attention, 32x32 swapped-operand =================
// (unchanged from round 6: 68 -> ~20 us; zero LDS, in-register softmax)
__global__ __launch_bounds__(256, 1) void attn_kernel(
        const u16* __restrict__ Q, const u16* __restrict__ Kb,
        const u16* __restrict__ Vt, u16* __restrict__ O, const int* __restrict__ start)
{
    const int tid = threadIdx.x, wave = tid >> 6, lane = tid & 63;
    const int q = lane & 31, hi = lane >> 5;
    const int h = blockIdx.y, hk = h >> 2;
    const int r0 = blockIdx.x * 128 + wave * 32;
    const int qrow = r0 + q;

    const u16* qp = Q + (size_t)qrow * HID + h * HD + hi * 8;
    bf16x8 Qf[8];
    #pragma unroll
    for (int kc = 0; kc < 8; kc++) Qf[kc] = *(const bf16x8*)(qp + kc * 16);

    const int startq = start[qrow];
    int jlo = startq;
    #pragma unroll
    for (int off = 1; off < 32; off <<= 1) jlo = min(jlo, __shfl_xor(jlo, off));
    const int jend = r0 + 31;

    float m = -INFINITY, l = 0.f;
    f32x16 o[4];
    #pragma unroll
    for (int dt = 0; dt < 4; dt++) o[dt] = (f32x16){};

    for (int j0 = (jlo & ~31); j0 <= jend; j0 += 32) {
        const u16* kp = Kb + (size_t)(j0 + q) * DKV + hk * HD + hi * 8;
        bf16x8 Kf[8];
        #pragma unroll
        for (int kc = 0; kc < 8; kc++) Kf[kc] = *(const bf16x8*)(kp + kc * 16);
        const u16* vp = Vt + (size_t)(hk * HD + q) * S_LEN + j0 + hi * 8;
        bf16x8 Vf[8];
        #pragma unroll
        for (int dt = 0; dt < 4; dt++)
            #pragma unroll
            for (int c = 0; c < 2; c++)
                Vf[dt * 2 + c] = *(const bf16x8*)(vp + (size_t)dt * 32 * S_LEN + c * 16);

        f32x16 s = (f32x16){};
        #pragma unroll
        for (int kc = 0; kc < 8; kc++)
            s = __builtin_amdgcn_mfma_f32_32x32x16_bf16(Kf[kc], Qf[kc], s, 0, 0, 0);

        float sv[16];
        float pmax = -INFINITY;
        #pragma unroll
        for (int r = 0; r < 16; r++) {
            int j = j0 + (r & 3) + 8 * (r >> 2) + 4 * hi;
            float x = (j <= qrow && j >= startq) ? s[r] : -INFINITY;
            sv[r] = x;
            pmax = fmaxf(pmax, x);
        }
        pmax = pairmax32(pmax);

        bool defer = __all(pmax <= m + 8.f);
        float mnew = m;
        if (!defer) {
            mnew = fmaxf(m, pmax);
            float corr = (m == -INFINITY) ? 0.f : __expf(m - mnew);
            l *= corr;
            #pragma unroll
            for (int dt = 0; dt < 4; dt++)
                #pragma unroll
                for (int r = 0; r < 16; r++) o[dt][r] *= corr;
            m = mnew;
        }

        float ps = 0.f;
        u16 pb[16];
        #pragma unroll
        for (int r = 0; r < 16; r++) {
            float p = (sv[r] == -INFINITY) ? 0.f : __expf(sv[r] - mnew);
            ps += p;
            pb[r] = f2bf(p);
        }
        l += pairsum32(ps);

        u32 w[8];
        #pragma unroll
        for (int i = 0; i < 8; i++) w[i] = (u32)pb[2 * i] | ((u32)pb[2 * i + 1] << 16);
        u32 x0, x1, y0, y1;
        plswap(w[0], w[2], x0, x1); plswap(w[1], w[3], y0, y1);
        u32x4 c0w = {x0, y0, x1, y1};
        bf16x8 P0 = __builtin_bit_cast(bf16x8, c0w);
        plswap(w[4], w[6], x0, x1); plswap(w[5], w[7], y0, y1);
        u32x4 c1w = {x0, y0, x1, y1};
        bf16x8 P1 = __builtin_bit_cast(bf16x8, c1w);

        #pragma unroll
        for (int dt = 0; dt < 4; dt++) {
            o[dt] = __builtin_amdgcn_mfma_f32_32x32x16_bf16(Vf[dt * 2 + 0], P0, o[dt], 0, 0, 0);
            o[dt] = __builtin_amdgcn_mfma_f32_32x32x16_bf16(Vf[dt * 2 + 1], P1, o[dt], 0, 0, 0);
        }
    }

    float inv = 1.0f / l;
    u16* op = O + (size_t)qrow * HID + h * HD + 4 * hi;
    #pragma unroll
    for (int dt = 0; dt < 4; dt++) {
        #pragma unroll
        for (int rb = 0; rb < 16; rb += 4) {
            u64 wd = (u64)f2bf(o[dt][rb + 0] * inv) |
                     ((u64)f2bf(o[dt][rb + 1] * inv) << 16) |
                     ((u64)f2bf(o[dt][rb + 2] * inv) << 32) |
                     ((u64)f2bf(o[dt][rb + 3] * inv) << 48);
            *(u64*)(op + dt * 32 + 2 * rb) = wd;
        }
    }
}

// ---------- launch ----------
extern "C" void kernel_launch(void* const* d_in, const int* in_sizes, int n_in,
                              void* d_out, int out_size, void* d_ws, size_t ws_size,
                              hipStream_t stream)
{
    char* ws = (char*)d_ws;
    const size_t MB = 1024 * 1024;
    int* flags = (int*)(ws + 0);
    int* start = (int*)(ws + 1024);
    u16* Xbf = (u16*)(ws + 16384);
    u16* WqT = (u16*)(ws + 16384 + 8 * MB);    // [2048][2048]
    u16* WkT = (u16*)(ws + 16384 + 16 * MB);   // [512][2048]
    u16* WvT = (u16*)(ws + 16384 + 18 * MB);   // [512][2048]
    u16* WoT = (u16*)(ws + 16384 + 20 * MB);
    u16* Qbf = (u16*)(ws + 16384 + 28 * MB);
    u16* Kbf = (u16*)(ws + 16384 + 36 * MB);
    u16* Vtb = (u16*)(ws + 16384 + 38 * MB);
    u16* Obf = (u16*)(ws + 16384 + 40 * MB);

    const void* X  = d_in[0];
    const unsigned char* mask = (const unsigned char*)d_in[1];
    const void* Wq = d_in[2];
    const void* Wk = d_in[3];
    const void* Wv = d_in[4];
    const void* Wo = d_in[5];

    detect_kernel<<<1, 64, 0, stream>>>((const u32*)X, mask, flags);
    extract_start_kernel<<<S_LEN, 64, 0, stream>>>(mask, start, flags);
    cvt_bf16_kernel<<<1024, 256, 0, stream>>>(X, Xbf, (long)S_LEN * HID, flags);
    transpose_cvt_kernel<<<dim3(HID / 32, HID / 32), dim3(32, 8), 0, stream>>>(Wq, WqT, HID, HID, flags);
    transpose_cvt_kernel<<<dim3(DKV / 32, HID / 32), dim3(32, 8), 0, stream>>>(Wk, WkT, HID, DKV, flags);
    transpose_cvt_kernel<<<dim3(DKV / 32, HID / 32), dim3(32, 8), 0, stream>>>(Wv, WvT, HID, DKV, flags);
    transpose_cvt_kernel<<<dim3(HID / 32, HID / 32), dim3(32, 8), 0, stream>>>(Wo, WoT, HID, HID, flags);

    gemm_qkv_kernel<<<dim3(24, HID / 128), 256, 0, stream>>>(Xbf, WqT, Qbf, Kbf, Vtb);

    attn_kernel<<<dim3(S_LEN / 128, NH), 256, 0, stream>>>(Qbf, Kbf, Vtb, Obf, start);

    gemm_bt_kernel<3><<<dim3(HID / 128, S_LEN / 128), 256, 0, stream>>>(Obf, WoT, d_out, S_LEN, HID, HID, 1.f);
}

// Round 8
// 139.357 us; speedup vs baseline: 1.8642x; 1.0623x over previous
//
#include <hip/hip_runtime.h>
#include <hip/hip_bf16.h>

// ---------- types ----------
typedef __attribute__((ext_vector_type(4)))  float f32x4;
typedef __attribute__((ext_vector_type(16))) float f32x16;
typedef __attribute__((ext_vector_type(8)))  short bf16x8;   // 8 bf16 in 4 VGPRs
typedef unsigned short u16;
typedef unsigned int   u32;
typedef unsigned long long u64;
typedef __attribute__((ext_vector_type(2))) u32 u32x2;
typedef __attribute__((ext_vector_type(4))) u32 u32x4;

#define S_LEN 2048
#define HID   2048
#define NH    16
#define NKV   4
#define HD    128
#define DKV   512          // NKV*HD
#define QK_SCALE 0.08838834764831845f   // 1/sqrt(128)

__device__ __forceinline__ u16 f2bf(float x) {              // RNE f32 -> bf16 bits
    u32 u = __builtin_bit_cast(u32, x);
    u32 r = (u + 0x7fffu + ((u >> 16) & 1u)) >> 16;
    return (u16)r;
}
__device__ __forceinline__ float bf2f(u16 b) {
    u32 u = ((u32)b) << 16;
    return __builtin_bit_cast(float, u);
}
__device__ __forceinline__ void gload_lds16(const void* g, void* l) {
    __builtin_amdgcn_global_load_lds(
        (const __attribute__((address_space(1))) u32*)g,
        (__attribute__((address_space(3))) u32*)l, 16, 0, 0);
}

// lane pair (L, L^32) exchange: x0/x1 per v_permlane32_swap semantics
__device__ __forceinline__ void plswap(u32 a, u32 b, u32& x0, u32& x1) {
#if __has_builtin(__builtin_amdgcn_permlane32_swap)
    u32x2 r = __builtin_amdgcn_permlane32_swap(a, b, false, false);
    x0 = r[0]; x1 = r[1];
#else
    u32 oa = (u32)__shfl_xor((int)a, 32);
    u32 ob = (u32)__shfl_xor((int)b, 32);
    int hi = (threadIdx.x & 63) >> 5;
    x0 = hi ? ob : a;
    x1 = hi ? b : oa;
#endif
}
__device__ __forceinline__ float pairmax32(float v) {
    u32 x0, x1; plswap(__builtin_bit_cast(u32, v), __builtin_bit_cast(u32, v), x0, x1);
    return fmaxf(__builtin_bit_cast(float, x0), __builtin_bit_cast(float, x1));
}
__device__ __forceinline__ float pairsum32(float v) {
    u32 x0, x1; plswap(__builtin_bit_cast(u32, v), __builtin_bit_cast(u32, v), x0, x1);
    return __builtin_bit_cast(float, x0) + __builtin_bit_cast(float, x1);
}

// ---------- dtype detection ----------
__global__ void detect_kernel(const u32* x, const unsigned char* mask, int* flags) {
    int lane = threadIdx.x;
    int big = 0, nz = 0;
    for (int i = lane; i < 256; i += 64) {
        u16 lo = (u16)(x[i] & 0xffffu);
        int e = (lo >> 7) & 0xff;
        big |= (e >= 0x83);
        nz  |= (lo != 0);
    }
    u64 bigb = __ballot(big);
    u64 nzb  = __ballot(nz);
    if (lane == 0) {
        flags[0] = (bigb != 0ull || nzb == 0ull) ? 1 : 0;   // 1 = f32 input
        flags[1] = (mask[2049] != 0) ? 1 : 4;               // mask elem width
    }
}

// ---------- per-row window start: start[i] = i+1 - count(true) ----------
__global__ void extract_start_kernel(const unsigned char* mask, int* start, const int* flags) {
    int i = blockIdx.x, lane = threadIdx.x;
    int w = flags[1];
    int cnt = 0;
    if (w == 1) {
        for (int j = lane; j < S_LEN; j += 64)
            cnt += (mask[(size_t)i * S_LEN + j] != 0);
    } else {
        const u32* m4 = (const u32*)mask;
        for (int j = lane; j < S_LEN; j += 64)
            cnt += (m4[(size_t)i * S_LEN + j] != 0);
    }
    #pragma unroll
    for (int off = 32; off; off >>= 1) cnt += __shfl_down(cnt, off);
    if (lane == 0) start[i] = i + 1 - cnt;
}

// ---------- convert (f32|bf16) -> bf16, contiguous ----------
__global__ void cvt_bf16_kernel(const void* in, u16* out, long n, const int* flags) {
    int isf32 = flags[0];
    long i = (long)blockIdx.x * blockDim.x + threadIdx.x;
    long stride = (long)gridDim.x * blockDim.x;
    if (isf32) {
        const float* p = (const float*)in;
        for (; i < n; i += stride) out[i] = f2bf(p[i]);
    } else {
        const u16* p = (const u16*)in;
        for (; i < n; i += stride) out[i] = p[i];
    }
}

// ---------- transpose + convert: W[K][N] -> WT[N][K] bf16 ----------
__global__ void transpose_cvt_kernel(const void* in, u16* out, int K, int N, const int* flags) {
    __shared__ float tile[32][33];
    int isf32 = flags[0];
    int n0 = blockIdx.x * 32, k0 = blockIdx.y * 32;
    for (int kk = threadIdx.y; kk < 32; kk += 8) {
        size_t idx = (size_t)(k0 + kk) * N + n0 + threadIdx.x;
        float v = isf32 ? ((const float*)in)[idx] : bf2f(((const u16*)in)[idx]);
        tile[kk][threadIdx.x] = v;
    }
    __syncthreads();
    for (int nn = threadIdx.y; nn < 32; nn += 8) {
        out[(size_t)(n0 + nn) * K + k0 + threadIdx.x] = f2bf(tile[threadIdx.x][nn]);
    }
}

// ================= fused QKV projection GEMM (128x64 tile, 2-phase dbuf) =================
// 4 waves in 2x2 quadrants of 64x32. LDS: A 2x16KB @0, B 2x8KB @32768 (48KB total).
__global__ __launch_bounds__(256) void gemm_qkv_kernel(
        const u16* __restrict__ A, const u16* __restrict__ BT,
        u16* __restrict__ Qo, u16* __restrict__ Ko, u16* __restrict__ Vto)
{
    __shared__ char smem[49152];
    const int tid = threadIdx.x;
    const int wave = tid >> 6, lane = tid & 63, g = lane >> 4, q = lane & 15;
    const int wr = wave >> 1, wc = wave & 1;
    const int m0 = blockIdx.y * 128, n0 = blockIdx.x * 64;
    const int K = HID;

    f32x4 acc[4][2];
    #pragma unroll
    for (int i = 0; i < 4; i++)
        #pragma unroll
        for (int j = 0; j < 2; j++) acc[i][j] = (f32x4){0.f, 0.f, 0.f, 0.f};

    auto stage = [&](int kt, int b) {
        const int kbase = kt << 6;
        #pragma unroll
        for (int it = 0; it < 4; ++it) {                 // A: 128 rows x 8 chunks
            int idx = it * 256 + tid;
            int row = idx >> 3, ch = idx & 7;
            int sch = ch ^ (row & 7);
            gload_lds16(A + (size_t)(m0 + row) * K + kbase + sch * 8,
                        smem + b * 16384 + idx * 16);
        }
        #pragma unroll
        for (int it = 0; it < 2; ++it) {                 // B: 64 rows x 8 chunks
            int idx = it * 256 + tid;
            int row = idx >> 3, ch = idx & 7;
            int sch = ch ^ (row & 7);
            gload_lds16(BT + (size_t)(n0 + row) * K + kbase + sch * 8,
                        smem + 32768 + b * 8192 + idx * 16);
        }
    };

    const int KT = K >> 6;
    stage(0, 0);
    __syncthreads();
    int cur = 0;
    for (int kt = 0; kt < KT; ++kt) {
        if (kt + 1 < KT) stage(kt + 1, cur ^ 1);   // next-tile loads retire under compute
        const char* sa = smem + cur * 16384;
        const char* sb = smem + 32768 + cur * 8192;
        #pragma unroll
        for (int kk = 0; kk < 2; ++kk) {
            bf16x8 af[4], bfr[2];
            #pragma unroll
            for (int i = 0; i < 4; i++) {
                int ra = wr * 64 + i * 16 + q;
                af[i] = *(const bf16x8*)(sa + ra * 128 + (((kk * 4 + g) ^ (ra & 7)) * 16));
            }
            #pragma unroll
            for (int j = 0; j < 2; j++) {
                int rb = wc * 32 + j * 16 + q;
                bfr[j] = *(const bf16x8*)(sb + rb * 128 + (((kk * 4 + g) ^ (rb & 7)) * 16));
            }
            #pragma unroll
            for (int i = 0; i < 4; i++)
                #pragma unroll
                for (int j = 0; j < 2; j++)
                    acc[i][j] = __builtin_amdgcn_mfma_f32_16x16x32_bf16(af[i], bfr[j], acc[i][j], 0, 0, 0);
        }
        __syncthreads();
        cur ^= 1;
    }
    #pragma unroll
    for (int i = 0; i < 4; i++) {
        #pragma unroll
        for (int j = 0; j < 2; j++) {
            #pragma unroll
            for (int r = 0; r < 4; r++) {
                int m = m0 + wr * 64 + i * 16 + g * 4 + r;
                int n = n0 + wc * 32 + j * 16 + q;
                float v = acc[i][j][r];
                if (n0 < 2048)      Qo[(size_t)m * HID + n] = f2bf(v * QK_SCALE);
                else if (n0 < 2560) Ko[(size_t)m * DKV + (n - 2048)] = f2bf(v);
                else                Vto[(size_t)(n - 2560) * S_LEN + m] = f2bf(v);
            }
        }
    }
}

// ---------- GEMM: C = A[M][K]*B (BT[N][K]); 128x64 tile, 2-phase dbuf ----------
//  MODE 0: bf16 out   MODE 3: f32 out
template <int MODE>
__global__ __launch_bounds__(256) void gemm_bt_kernel(
        const u16* __restrict__ A, const u16* __restrict__ BT, void* __restrict__ Cv,
        int M, int N, int K, float scale)
{
    __shared__ char smem[49152];
    const int tid = threadIdx.x;
    const int wave = tid >> 6, lane = tid & 63, g = lane >> 4, q = lane & 15;
    const int wr = wave >> 1, wc = wave & 1;
    const int m0 = blockIdx.y * 128, n0 = blockIdx.x * 64;

    f32x4 acc[4][2];
    #pragma unroll
    for (int i = 0; i < 4; i++)
        #pragma unroll
        for (int j = 0; j < 2; j++) acc[i][j] = (f32x4){0.f, 0.f, 0.f, 0.f};

    auto stage = [&](int kt, int b) {
        const int kbase = kt << 6;
        #pragma unroll
        for (int it = 0; it < 4; ++it) {
            int idx = it * 256 + tid;
            int row = idx >> 3, ch = idx & 7;
            int sch = ch ^ (row & 7);
            gload_lds16(A + (size_t)(m0 + row) * K + kbase + sch * 8,
                        smem + b * 16384 + idx * 16);
        }
        #pragma unroll
        for (int it = 0; it < 2; ++it) {
            int idx = it * 256 + tid;
            int row = idx >> 3, ch = idx & 7;
            int sch = ch ^ (row & 7);
            gload_lds16(BT + (size_t)(n0 + row) * K + kbase + sch * 8,
                        smem + 32768 + b * 8192 + idx * 16);
        }
    };

    const int KT = K >> 6;
    stage(0, 0);
    __syncthreads();
    int cur = 0;
    for (int kt = 0; kt < KT; ++kt) {
        if (kt + 1 < KT) stage(kt + 1, cur ^ 1);
        const char* sa = smem + cur * 16384;
        const char* sb = smem + 32768 + cur * 8192;
        #pragma unroll
        for (int kk = 0; kk < 2; ++kk) {
            bf16x8 af[4], bfr[2];
            #pragma unroll
            for (int i = 0; i < 4; i++) {
                int ra = wr * 64 + i * 16 + q;
                af[i] = *(const bf16x8*)(sa + ra * 128 + (((kk * 4 + g) ^ (ra & 7)) * 16));
            }
            #pragma unroll
            for (int j = 0; j < 2; j++) {
                int rb = wc * 32 + j * 16 + q;
                bfr[j] = *(const bf16x8*)(sb + rb * 128 + (((kk * 4 + g) ^ (rb & 7)) * 16));
            }
            #pragma unroll
            for (int i = 0; i < 4; i++)
                #pragma unroll
                for (int j = 0; j < 2; j++)
                    acc[i][j] = __builtin_amdgcn_mfma_f32_16x16x32_bf16(af[i], bfr[j], acc[i][j], 0, 0, 0);
        }
        __syncthreads();
        cur ^= 1;
    }
    #pragma unroll
    for (int i = 0; i < 4; i++) {
        #pragma unroll
        for (int j = 0; j < 2; j++) {
            #pragma unroll
            for (int r = 0; r < 4; r++) {
                int m = m0 + wr * 64 + i * 16 + g * 4 + r;
                int n = n0 + wc * 32 + j * 16 + q;
                float v = acc[i][j][r] * scale;
                if (MODE == 3) ((float*)Cv)[(size_t)m * N + n] = v;
                else           ((u16*)Cv)[(size_t)m * N + n] = f2bf(v);
            }
        }
    }
}

// ================= adaptive-window flash attention, 32x32 swapped-operand =================
// (unchanged from round 6: zero LDS, in-register softmax)
__global__ __launch_bounds__(256, 1) void attn_kernel(
        const u16* __restrict__ Q, const u16* __restrict__ Kb,
        const u16* __restrict__ Vt, u16* __restrict__ O, const int* __restrict__ start)
{
    const int tid = threadIdx.x, wave = tid >> 6, lane = tid & 63;
    const int q = lane & 31, hi = lane >> 5;
    const int h = blockIdx.y, hk = h >> 2;
    const int r0 = blockIdx.x * 128 + wave * 32;
    const int qrow = r0 + q;

    const u16* qp = Q + (size_t)qrow * HID + h * HD + hi * 8;
    bf16x8 Qf[8];
    #pragma unroll
    for (int kc = 0; kc < 8; kc++) Qf[kc] = *(const bf16x8*)(qp + kc * 16);

    const int startq = start[qrow];
    int jlo = startq;
    #pragma unroll
    for (int off = 1; off < 32; off <<= 1) jlo = min(jlo, __shfl_xor(jlo, off));
    const int jend = r0 + 31;

    float m = -INFINITY, l = 0.f;
    f32x16 o[4];
    #pragma unroll
    for (int dt = 0; dt < 4; dt++) o[dt] = (f32x16){};

    for (int j0 = (jlo & ~31); j0 <= jend; j0 += 32) {
        const u16* kp = Kb + (size_t)(j0 + q) * DKV + hk * HD + hi * 8;
        bf16x8 Kf[8];
        #pragma unroll
        for (int kc = 0; kc < 8; kc++) Kf[kc] = *(const bf16x8*)(kp + kc * 16);
        const u16* vp = Vt + (size_t)(hk * HD + q) * S_LEN + j0 + hi * 8;
        bf16x8 Vf[8];
        #pragma unroll
        for (int dt = 0; dt < 4; dt++)
            #pragma unroll
            for (int c = 0; c < 2; c++)
                Vf[dt * 2 + c] = *(const bf16x8*)(vp + (size_t)dt * 32 * S_LEN + c * 16);

        f32x16 s = (f32x16){};
        #pragma unroll
        for (int kc = 0; kc < 8; kc++)
            s = __builtin_amdgcn_mfma_f32_32x32x16_bf16(Kf[kc], Qf[kc], s, 0, 0, 0);

        float sv[16];
        float pmax = -INFINITY;
        #pragma unroll
        for (int r = 0; r < 16; r++) {
            int j = j0 + (r & 3) + 8 * (r >> 2) + 4 * hi;
            float x = (j <= qrow && j >= startq) ? s[r] : -INFINITY;
            sv[r] = x;
            pmax = fmaxf(pmax, x);
        }
        pmax = pairmax32(pmax);

        bool defer = __all(pmax <= m + 8.f);
        float mnew = m;
        if (!defer) {
            mnew = fmaxf(m, pmax);
            float corr = (m == -INFINITY) ? 0.f : __expf(m - mnew);
            l *= corr;
            #pragma unroll
            for (int dt = 0; dt < 4; dt++)
                #pragma unroll
                for (int r = 0; r < 16; r++) o[dt][r] *= corr;
            m = mnew;
        }

        float ps = 0.f;
        u16 pb[16];
        #pragma unroll
        for (int r = 0; r < 16; r++) {
            float p = (sv[r] == -INFINITY) ? 0.f : __expf(sv[r] - mnew);
            ps += p;
            pb[r] = f2bf(p);
        }
        l += pairsum32(ps);

        u32 w[8];
        #pragma unroll
        for (int i = 0; i < 8; i++) w[i] = (u32)pb[2 * i] | ((u32)pb[2 * i + 1] << 16);
        u32 x0, x1, y0, y1;
        plswap(w[0], w[2], x0, x1); plswap(w[1], w[3], y0, y1);
        u32x4 c0w = {x0, y0, x1, y1};
        bf16x8 P0 = __builtin_bit_cast(bf16x8, c0w);
        plswap(w[4], w[6], x0, x1); plswap(w[5], w[7], y0, y1);
        u32x4 c1w = {x0, y0, x1, y1};
        bf16x8 P1 = __builtin_bit_cast(bf16x8, c1w);

        #pragma unroll
        for (int dt = 0; dt < 4; dt++) {
            o[dt] = __builtin_amdgcn_mfma_f32_32x32x16_bf16(Vf[dt * 2 + 0], P0, o[dt], 0, 0, 0);
            o[dt] = __builtin_amdgcn_mfma_f32_32x32x16_bf16(Vf[dt * 2 + 1], P1, o[dt], 0, 0, 0);
        }
    }

    float inv = 1.0f / l;
    u16* op = O + (size_t)qrow * HID + h * HD + 4 * hi;
    #pragma unroll
    for (int dt = 0; dt < 4; dt++) {
        #pragma unroll
        for (int rb = 0; rb < 16; rb += 4) {
            u64 wd = (u64)f2bf(o[dt][rb + 0] * inv) |
                     ((u64)f2bf(o[dt][rb + 1] * inv) << 16) |
                     ((u64)f2bf(o[dt][rb + 2] * inv) << 32) |
                     ((u64)f2bf(o[dt][rb + 3] * inv) << 48);
            *(u64*)(op + dt * 32 + 2 * rb) = wd;
        }
    }
}

// ---------- launch ----------
extern "C" void kernel_launch(void* const* d_in, const int* in_sizes, int n_in,
                              void* d_out, int out_size, void* d_ws, size_t ws_size,
                              hipStream_t stream)
{
    char* ws = (char*)d_ws;
    const size_t MB = 1024 * 1024;
    int* flags = (int*)(ws + 0);
    int* start = (int*)(ws + 1024);
    u16* Xbf = (u16*)(ws + 16384);
    u16* WqT = (u16*)(ws + 16384 + 8 * MB);    // [2048][2048]
    u16* WkT = (u16*)(ws + 16384 + 16 * MB);   // [512][2048]
    u16* WvT = (u16*)(ws + 16384 + 18 * MB);   // [512][2048]
    u16* WoT = (u16*)(ws + 16384 + 20 * MB);
    u16* Qbf = (u16*)(ws + 16384 + 28 * MB);
    u16* Kbf = (u16*)(ws + 16384 + 36 * MB);
    u16* Vtb = (u16*)(ws + 16384 + 38 * MB);
    u16* Obf = (u16*)(ws + 16384 + 40 * MB);

    const void* X  = d_in[0];
    const unsigned char* mask = (const unsigned char*)d_in[1];
    const void* Wq = d_in[2];
    const void* Wk = d_in[3];
    const void* Wv = d_in[4];
    const void* Wo = d_in[5];

    detect_kernel<<<1, 64, 0, stream>>>((const u32*)X, mask, flags);
    extract_start_kernel<<<S_LEN, 64, 0, stream>>>(mask, start, flags);
    cvt_bf16_kernel<<<1024, 256, 0, stream>>>(X, Xbf, (long)S_LEN * HID, flags);
    transpose_cvt_kernel<<<dim3(HID / 32, HID / 32), dim3(32, 8), 0, stream>>>(Wq, WqT, HID, HID, flags);
    transpose_cvt_kernel<<<dim3(DKV / 32, HID / 32), dim3(32, 8), 0, stream>>>(Wk, WkT, HID, DKV, flags);
    transpose_cvt_kernel<<<dim3(DKV / 32, HID / 32), dim3(32, 8), 0, stream>>>(Wv, WvT, HID, DKV, flags);
    transpose_cvt_kernel<<<dim3(HID / 32, HID / 32), dim3(32, 8), 0, stream>>>(Wo, WoT, HID, HID, flags);

    gemm_qkv_kernel<<<dim3(48, HID / 128), 256, 0, stream>>>(Xbf, WqT, Qbf, Kbf, Vtb);

    attn_kernel<<<dim3(S_LEN / 128, NH), 256, 0, stream>>>(Qbf, Kbf, Vtb, Obf, start);

    gemm_bt_kernel<3><<<dim3(HID / 64, S_LEN / 128), 256, 0, stream>>>(Obf, WoT, d_out, S_LEN, HID, HID, 1.f);
}

// Round 9
// 118.311 us; speedup vs baseline: 2.1959x; 1.1779x over previous
//
#include <hip/hip_runtime.h>
#include <hip/hip_bf16.h>

// ---------- types ----------
typedef __attribute__((ext_vector_type(4)))  float f32x4;
typedef __attribute__((ext_vector_type(16))) float f32x16;
typedef __attribute__((ext_vector_type(8)))  short bf16x8;   // 8 bf16 in 4 VGPRs
typedef unsigned short u16;
typedef unsigned int   u32;
typedef unsigned long long u64;
typedef __attribute__((ext_vector_type(2))) u32 u32x2;
typedef __attribute__((ext_vector_type(4))) u32 u32x4;

#define S_LEN 2048
#define HID   2048
#define NH    16
#define NKV   4
#define HD    128
#define DKV   512          // NKV*HD
#define QK_SCALE 0.08838834764831845f   // 1/sqrt(128)

__device__ __forceinline__ u16 f2bf(float x) {              // RNE f32 -> bf16 bits
    u32 u = __builtin_bit_cast(u32, x);
    u32 r = (u + 0x7fffu + ((u >> 16) & 1u)) >> 16;
    return (u16)r;
}
__device__ __forceinline__ float bf2f(u16 b) {
    u32 u = ((u32)b) << 16;
    return __builtin_bit_cast(float, u);
}
__device__ __forceinline__ void gload_lds16(const void* g, void* l) {
    __builtin_amdgcn_global_load_lds(
        (const __attribute__((address_space(1))) u32*)g,
        (__attribute__((address_space(3))) u32*)l, 16, 0, 0);
}
__device__ __forceinline__ u32x4 pack8(const u16* o) {
    u32x4 r;
    r[0] = (u32)o[0] | ((u32)o[1] << 16);
    r[1] = (u32)o[2] | ((u32)o[3] << 16);
    r[2] = (u32)o[4] | ((u32)o[5] << 16);
    r[3] = (u32)o[6] | ((u32)o[7] << 16);
    return r;
}

// lane pair (L, L^32) exchange: x0/x1 per v_permlane32_swap semantics
__device__ __forceinline__ void plswap(u32 a, u32 b, u32& x0, u32& x1) {
#if __has_builtin(__builtin_amdgcn_permlane32_swap)
    u32x2 r = __builtin_amdgcn_permlane32_swap(a, b, false, false);
    x0 = r[0]; x1 = r[1];
#else
    u32 oa = (u32)__shfl_xor((int)a, 32);
    u32 ob = (u32)__shfl_xor((int)b, 32);
    int hi = (threadIdx.x & 63) >> 5;
    x0 = hi ? ob : a;
    x1 = hi ? b : oa;
#endif
}
__device__ __forceinline__ float pairmax32(float v) {
    u32 x0, x1; plswap(__builtin_bit_cast(u32, v), __builtin_bit_cast(u32, v), x0, x1);
    return fmaxf(__builtin_bit_cast(float, x0), __builtin_bit_cast(float, x1));
}
__device__ __forceinline__ float pairsum32(float v) {
    u32 x0, x1; plswap(__builtin_bit_cast(u32, v), __builtin_bit_cast(u32, v), x0, x1);
    return __builtin_bit_cast(float, x0) + __builtin_bit_cast(float, x1);
}

// ================= fused preprocessing =================
// grid = NT_W (weight transposes) + NB_CVT (X cvt) + NB_START (mask popcount)
// Every block re-derives isf32 from X[0..255] (L2-broadcast, ~free); no flags dependency.
#define NTQ 1024           // Wq 2048x2048: 32x32 tiles of 64x64
#define NTK 256            // Wk 2048x512
#define NTV 256            // Wv 2048x512
#define NTO 1024           // Wo 2048x2048
#define NT_W (NTQ + NTK + NTV + NTO)          // 2560
#define NB_CVT 1024        // X: 4M elems, 4096/block
#define NB_START 128       // 16 mask rows/block
#define NB_PREP (NT_W + NB_CVT + NB_START)    // 3712

__global__ __launch_bounds__(256) void prep_kernel(
        const u32* __restrict__ X, const unsigned char* __restrict__ mask,
        const void* __restrict__ Wq, const void* __restrict__ Wk,
        const void* __restrict__ Wv, const void* __restrict__ Wo,
        u16* __restrict__ Xbf, u16* __restrict__ WqT, u16* __restrict__ WkT,
        u16* __restrict__ WvT, u16* __restrict__ WoT, int* __restrict__ start)
{
    __shared__ float tile[64][65];
    const int tid = threadIdx.x, lane = tid & 63, wave = tid >> 6;

    // inline dtype detect (wave-uniform, identical in all waves)
    int big = 0, nz = 0;
    #pragma unroll
    for (int i = 0; i < 4; i++) {
        u32 v = X[lane + i * 64];
        u16 lo = (u16)(v & 0xffffu);
        int e = (lo >> 7) & 0xff;
        big |= (e >= 0x83);
        nz  |= (lo != 0);
    }
    const int isf32 = (__ballot(big) != 0ull || __ballot(nz) == 0ull) ? 1 : 0;

    const int b = blockIdx.x;
    if (b < NT_W) {
        // ---- weight transpose+convert: 64x64 tile ----
        const void* src; u16* dst; int N, ty;
        if (b < NTQ)                  { src = Wq; dst = WqT; N = 2048; ty = b; }
        else if (b < NTQ + NTK)       { src = Wk; dst = WkT; N = 512;  ty = b - NTQ; }
        else if (b < NTQ + NTK + NTV) { src = Wv; dst = WvT; N = 512;  ty = b - NTQ - NTK; }
        else                          { src = Wo; dst = WoT; N = 2048; ty = b - NTQ - NTK - NTV; }
        const int K = 2048;
        const int ntx = N >> 6;
        const int k0 = (ty / ntx) << 6, n0 = (ty % ntx) << 6;
        const int kk = tid >> 4, cg = (tid & 15) << 2;
        if (isf32) {
            const float* W = (const float*)src;
            #pragma unroll
            for (int it = 0; it < 4; it++) {
                f32x4 v = *(const f32x4*)(W + (size_t)(k0 + kk + it * 16) * N + n0 + cg);
                tile[kk + it * 16][cg + 0] = v[0]; tile[kk + it * 16][cg + 1] = v[1];
                tile[kk + it * 16][cg + 2] = v[2]; tile[kk + it * 16][cg + 3] = v[3];
            }
        } else {
            const u16* W = (const u16*)src;
            #pragma unroll
            for (int it = 0; it < 4; it++) {
                u64 v = *(const u64*)(W + (size_t)(k0 + kk + it * 16) * N + n0 + cg);
                tile[kk + it * 16][cg + 0] = bf2f((u16)(v));
                tile[kk + it * 16][cg + 1] = bf2f((u16)(v >> 16));
                tile[kk + it * 16][cg + 2] = bf2f((u16)(v >> 32));
                tile[kk + it * 16][cg + 3] = bf2f((u16)(v >> 48));
            }
        }
        __syncthreads();
        const int nn = tid >> 2;
        #pragma unroll
        for (int it = 0; it < 2; it++) {
            int kof = ((tid & 3) + it * 4) << 3;
            u16 ob[8];
            #pragma unroll
            for (int j = 0; j < 8; j++) ob[j] = f2bf(tile[kof + j][nn]);
            *(u32x4*)(dst + (size_t)(n0 + nn) * K + k0 + kof) = pack8(ob);
        }
    } else if (b < NT_W + NB_CVT) {
        // ---- X -> bf16, 16 elems/thread ----
        const long base = ((long)(b - NT_W) * 256 + tid) * 16;
        u16 ob[16];
        if (isf32) {
            const float* p = (const float*)X;
            #pragma unroll
            for (int c = 0; c < 4; c++) {
                f32x4 v = *(const f32x4*)(p + base + c * 4);
                ob[c * 4 + 0] = f2bf(v[0]); ob[c * 4 + 1] = f2bf(v[1]);
                ob[c * 4 + 2] = f2bf(v[2]); ob[c * 4 + 3] = f2bf(v[3]);
            }
        } else {
            const u16* p = (const u16*)X;
            #pragma unroll
            for (int j = 0; j < 16; j++) ob[j] = p[base + j];
        }
        *(u32x4*)(Xbf + base) = pack8(ob);
        *(u32x4*)(Xbf + base + 8) = pack8(ob + 8);
    } else {
        // ---- mask -> start[i] = i+1 - popcount(row i); wave handles 4 rows ----
        const int b3 = b - NT_W - NB_CVT;
        const bool w1 = (mask[2049] != 0);      // 1-byte vs 4-byte elements
        #pragma unroll
        for (int rr = 0; rr < 4; rr++) {
            const int r = b3 * 16 + wave * 4 + rr;
            int cnt = 0;
            if (w1) {
                const u32* row = (const u32*)(mask + (size_t)r * S_LEN);
                #pragma unroll
                for (int i = 0; i < 8; i++) {
                    u32 v = row[lane + i * 64];
                    cnt += (int)(((v & 0x01010101u) * 0x01010101u) >> 24);
                }
            } else {
                const u32* row = (const u32*)mask + (size_t)r * S_LEN;
                #pragma unroll
                for (int i = 0; i < 32; i++) cnt += (row[lane + i * 64] != 0);
            }
            #pragma unroll
            for (int off = 32; off; off >>= 1) cnt += __shfl_down(cnt, off);
            if (lane == 0) start[r] = r + 1 - cnt;
        }
    }
}

// ================= fused QKV projection GEMM (128x64 tile, 2-phase dbuf, XCD swizzle) =================
__global__ __launch_bounds__(256) void gemm_qkv_kernel(
        const u16* __restrict__ A, const u16* __restrict__ BT,
        u16* __restrict__ Qo, u16* __restrict__ Ko, u16* __restrict__ Vto)
{
    __shared__ char smem[49152];
    const int tid = threadIdx.x;
    const int wave = tid >> 6, lane = tid & 63, g = lane >> 4, q = lane & 15;
    const int wr = wave >> 1, wc = wave & 1;
    // bijective XCD swizzle: chunk of nwg/8 consecutive logical tiles per XCD
    const int gx = gridDim.x, nwg = gx * gridDim.y;
    const int wg = blockIdx.x + blockIdx.y * gx;
    const int swz = (wg & 7) * (nwg >> 3) + (wg >> 3);
    const int m0 = (swz / gx) * 128, n0 = (swz % gx) * 64;
    const int K = HID;

    f32x4 acc[4][2];
    #pragma unroll
    for (int i = 0; i < 4; i++)
        #pragma unroll
        for (int j = 0; j < 2; j++) acc[i][j] = (f32x4){0.f, 0.f, 0.f, 0.f};

    auto stage = [&](int kt, int b) {
        const int kbase = kt << 6;
        #pragma unroll
        for (int it = 0; it < 4; ++it) {                 // A: 128 rows x 8 chunks
            int idx = it * 256 + tid;
            int row = idx >> 3, ch = idx & 7;
            int sch = ch ^ (row & 7);
            gload_lds16(A + (size_t)(m0 + row) * K + kbase + sch * 8,
                        smem + b * 16384 + idx * 16);
        }
        #pragma unroll
        for (int it = 0; it < 2; ++it) {                 // B: 64 rows x 8 chunks
            int idx = it * 256 + tid;
            int row = idx >> 3, ch = idx & 7;
            int sch = ch ^ (row & 7);
            gload_lds16(BT + (size_t)(n0 + row) * K + kbase + sch * 8,
                        smem + 32768 + b * 8192 + idx * 16);
        }
    };

    const int KT = K >> 6;
    stage(0, 0);
    __syncthreads();
    int cur = 0;
    for (int kt = 0; kt < KT; ++kt) {
        if (kt + 1 < KT) stage(kt + 1, cur ^ 1);   // next-tile loads retire under compute
        const char* sa = smem + cur * 16384;
        const char* sb = smem + 32768 + cur * 8192;
        #pragma unroll
        for (int kk = 0; kk < 2; ++kk) {
            bf16x8 af[4], bfr[2];
            #pragma unroll
            for (int i = 0; i < 4; i++) {
                int ra = wr * 64 + i * 16 + q;
                af[i] = *(const bf16x8*)(sa + ra * 128 + (((kk * 4 + g) ^ (ra & 7)) * 16));
            }
            #pragma unroll
            for (int j = 0; j < 2; j++) {
                int rb = wc * 32 + j * 16 + q;
                bfr[j] = *(const bf16x8*)(sb + rb * 128 + (((kk * 4 + g) ^ (rb & 7)) * 16));
            }
            #pragma unroll
            for (int i = 0; i < 4; i++)
                #pragma unroll
                for (int j = 0; j < 2; j++)
                    acc[i][j] = __builtin_amdgcn_mfma_f32_16x16x32_bf16(af[i], bfr[j], acc[i][j], 0, 0, 0);
        }
        __syncthreads();
        cur ^= 1;
    }
    #pragma unroll
    for (int i = 0; i < 4; i++) {
        #pragma unroll
        for (int j = 0; j < 2; j++) {
            #pragma unroll
            for (int r = 0; r < 4; r++) {
                int m = m0 + wr * 64 + i * 16 + g * 4 + r;
                int n = n0 + wc * 32 + j * 16 + q;
                float v = acc[i][j][r];
                if (n0 < 2048)      Qo[(size_t)m * HID + n] = f2bf(v * QK_SCALE);
                else if (n0 < 2560) Ko[(size_t)m * DKV + (n - 2048)] = f2bf(v);
                else                Vto[(size_t)(n - 2560) * S_LEN + m] = f2bf(v);
            }
        }
    }
}

// ---------- GEMM: C = A[M][K]*B (BT[N][K]); 128x64 tile, 2-phase dbuf, XCD swizzle ----------
//  MODE 0: bf16 out   MODE 3: f32 out
template <int MODE>
__global__ __launch_bounds__(256) void gemm_bt_kernel(
        const u16* __restrict__ A, const u16* __restrict__ BT, void* __restrict__ Cv,
        int M, int N, int K, float scale)
{
    __shared__ char smem[49152];
    const int tid = threadIdx.x;
    const int wave = tid >> 6, lane = tid & 63, g = lane >> 4, q = lane & 15;
    const int wr = wave >> 1, wc = wave & 1;
    const int gx = gridDim.x, nwg = gx * gridDim.y;
    const int wg = blockIdx.x + blockIdx.y * gx;
    const int swz = (nwg & 7) == 0 ? ((wg & 7) * (nwg >> 3) + (wg >> 3)) : wg;
    const int m0 = (swz / gx) * 128, n0 = (swz % gx) * 64;

    f32x4 acc[4][2];
    #pragma unroll
    for (int i = 0; i < 4; i++)
        #pragma unroll
        for (int j = 0; j < 2; j++) acc[i][j] = (f32x4){0.f, 0.f, 0.f, 0.f};

    auto stage = [&](int kt, int b) {
        const int kbase = kt << 6;
        #pragma unroll
        for (int it = 0; it < 4; ++it) {
            int idx = it * 256 + tid;
            int row = idx >> 3, ch = idx & 7;
            int sch = ch ^ (row & 7);
            gload_lds16(A + (size_t)(m0 + row) * K + kbase + sch * 8,
                        smem + b * 16384 + idx * 16);
        }
        #pragma unroll
        for (int it = 0; it < 2; ++it) {
            int idx = it * 256 + tid;
            int row = idx >> 3, ch = idx & 7;
            int sch = ch ^ (row & 7);
            gload_lds16(BT + (size_t)(n0 + row) * K + kbase + sch * 8,
                        smem + 32768 + b * 8192 + idx * 16);
        }
    };

    const int KT = K >> 6;
    stage(0, 0);
    __syncthreads();
    int cur = 0;
    for (int kt = 0; kt < KT; ++kt) {
        if (kt + 1 < KT) stage(kt + 1, cur ^ 1);
        const char* sa = smem + cur * 16384;
        const char* sb = smem + 32768 + cur * 8192;
        #pragma unroll
        for (int kk = 0; kk < 2; ++kk) {
            bf16x8 af[4], bfr[2];
            #pragma unroll
            for (int i = 0; i < 4; i++) {
                int ra = wr * 64 + i * 16 + q;
                af[i] = *(const bf16x8*)(sa + ra * 128 + (((kk * 4 + g) ^ (ra & 7)) * 16));
            }
            #pragma unroll
            for (int j = 0; j < 2; j++) {
                int rb = wc * 32 + j * 16 + q;
                bfr[j] = *(const bf16x8*)(sb + rb * 128 + (((kk * 4 + g) ^ (rb & 7)) * 16));
            }
            #pragma unroll
            for (int i = 0; i < 4; i++)
                #pragma unroll
                for (int j = 0; j < 2; j++)
                    acc[i][j] = __builtin_amdgcn_mfma_f32_16x16x32_bf16(af[i], bfr[j], acc[i][j], 0, 0, 0);
        }
        __syncthreads();
        cur ^= 1;
    }
    #pragma unroll
    for (int i = 0; i < 4; i++) {
        #pragma unroll
        for (int j = 0; j < 2; j++) {
            #pragma unroll
            for (int r = 0; r < 4; r++) {
                int m = m0 + wr * 64 + i * 16 + g * 4 + r;
                int n = n0 + wc * 32 + j * 16 + q;
                float v = acc[i][j][r] * scale;
                if (MODE == 3) ((float*)Cv)[(size_t)m * N + n] = v;
                else           ((u16*)Cv)[(size_t)m * N + n] = f2bf(v);
            }
        }
    }
}

// ================= adaptive-window flash attention, 32x32 swapped-operand =================
// (unchanged: zero LDS, in-register softmax)
__global__ __launch_bounds__(256, 1) void attn_kernel(
        const u16* __restrict__ Q, const u16* __restrict__ Kb,
        const u16* __restrict__ Vt, u16* __restrict__ O, const int* __restrict__ start)
{
    const int tid = threadIdx.x, wave = tid >> 6, lane = tid & 63;
    const int q = lane & 31, hi = lane >> 5;
    const int h = blockIdx.y, hk = h >> 2;
    const int r0 = blockIdx.x * 128 + wave * 32;
    const int qrow = r0 + q;

    const u16* qp = Q + (size_t)qrow * HID + h * HD + hi * 8;
    bf16x8 Qf[8];
    #pragma unroll
    for (int kc = 0; kc < 8; kc++) Qf[kc] = *(const bf16x8*)(qp + kc * 16);

    const int startq = start[qrow];
    int jlo = startq;
    #pragma unroll
    for (int off = 1; off < 32; off <<= 1) jlo = min(jlo, __shfl_xor(jlo, off));
    const int jend = r0 + 31;

    float m = -INFINITY, l = 0.f;
    f32x16 o[4];
    #pragma unroll
    for (int dt = 0; dt < 4; dt++) o[dt] = (f32x16){};

    for (int j0 = (jlo & ~31); j0 <= jend; j0 += 32) {
        const u16* kp = Kb + (size_t)(j0 + q) * DKV + hk * HD + hi * 8;
        bf16x8 Kf[8];
        #pragma unroll
        for (int kc = 0; kc < 8; kc++) Kf[kc] = *(const bf16x8*)(kp + kc * 16);
        const u16* vp = Vt + (size_t)(hk * HD + q) * S_LEN + j0 + hi * 8;
        bf16x8 Vf[8];
        #pragma unroll
        for (int dt = 0; dt < 4; dt++)
            #pragma unroll
            for (int c = 0; c < 2; c++)
                Vf[dt * 2 + c] = *(const bf16x8*)(vp + (size_t)dt * 32 * S_LEN + c * 16);

        f32x16 s = (f32x16){};
        #pragma unroll
        for (int kc = 0; kc < 8; kc++)
            s = __builtin_amdgcn_mfma_f32_32x32x16_bf16(Kf[kc], Qf[kc], s, 0, 0, 0);

        float sv[16];
        float pmax = -INFINITY;
        #pragma unroll
        for (int r = 0; r < 16; r++) {
            int j = j0 + (r & 3) + 8 * (r >> 2) + 4 * hi;
            float x = (j <= qrow && j >= startq) ? s[r] : -INFINITY;
            sv[r] = x;
            pmax = fmaxf(pmax, x);
        }
        pmax = pairmax32(pmax);

        bool defer = __all(pmax <= m + 8.f);
        float mnew = m;
        if (!defer) {
            mnew = fmaxf(m, pmax);
            float corr = (m == -INFINITY) ? 0.f : __expf(m - mnew);
            l *= corr;
            #pragma unroll
            for (int dt = 0; dt < 4; dt++)
                #pragma unroll
                for (int r = 0; r < 16; r++) o[dt][r] *= corr;
            m = mnew;
        }

        float ps = 0.f;
        u16 pb[16];
        #pragma unroll
        for (int r = 0; r < 16; r++) {
            float p = (sv[r] == -INFINITY) ? 0.f : __expf(sv[r] - mnew);
            ps += p;
            pb[r] = f2bf(p);
        }
        l += pairsum32(ps);

        u32 w[8];
        #pragma unroll
        for (int i = 0; i < 8; i++) w[i] = (u32)pb[2 * i] | ((u32)pb[2 * i + 1] << 16);
        u32 x0, x1, y0, y1;
        plswap(w[0], w[2], x0, x1); plswap(w[1], w[3], y0, y1);
        u32x4 c0w = {x0, y0, x1, y1};
        bf16x8 P0 = __builtin_bit_cast(bf16x8, c0w);
        plswap(w[4], w[6], x0, x1); plswap(w[5], w[7], y0, y1);
        u32x4 c1w = {x0, y0, x1, y1};
        bf16x8 P1 = __builtin_bit_cast(bf16x8, c1w);

        #pragma unroll
        for (int dt = 0; dt < 4; dt++) {
            o[dt] = __builtin_amdgcn_mfma_f32_32x32x16_bf16(Vf[dt * 2 + 0], P0, o[dt], 0, 0, 0);
            o[dt] = __builtin_amdgcn_mfma_f32_32x32x16_bf16(Vf[dt * 2 + 1], P1, o[dt], 0, 0, 0);
        }
    }

    float inv = 1.0f / l;
    u16* op = O + (size_t)qrow * HID + h * HD + 4 * hi;
    #pragma unroll
    for (int dt = 0; dt < 4; dt++) {
        #pragma unroll
        for (int rb = 0; rb < 16; rb += 4) {
            u64 wd = (u64)f2bf(o[dt][rb + 0] * inv) |
                     ((u64)f2bf(o[dt][rb + 1] * inv) << 16) |
                     ((u64)f2bf(o[dt][rb + 2] * inv) << 32) |
                     ((u64)f2bf(o[dt][rb + 3] * inv) << 48);
            *(u64*)(op + dt * 32 + 2 * rb) = wd;
        }
    }
}

// ---------- launch ----------
extern "C" void kernel_launch(void* const* d_in, const int* in_sizes, int n_in,
                              void* d_out, int out_size, void* d_ws, size_t ws_size,
                              hipStream_t stream)
{
    char* ws = (char*)d_ws;
    const size_t MB = 1024 * 1024;
    int* start = (int*)(ws + 1024);
    u16* Xbf = (u16*)(ws + 16384);
    u16* WqT = (u16*)(ws + 16384 + 8 * MB);    // [2048][2048]
    u16* WkT = (u16*)(ws + 16384 + 16 * MB);   // [512][2048]
    u16* WvT = (u16*)(ws + 16384 + 18 * MB);   // [512][2048]
    u16* WoT = (u16*)(ws + 16384 + 20 * MB);
    u16* Qbf = (u16*)(ws + 16384 + 28 * MB);
    u16* Kbf = (u16*)(ws + 16384 + 36 * MB);
    u16* Vtb = (u16*)(ws + 16384 + 38 * MB);
    u16* Obf = (u16*)(ws + 16384 + 40 * MB);

    const void* X  = d_in[0];
    const unsigned char* mask = (const unsigned char*)d_in[1];
    const void* Wq = d_in[2];
    const void* Wk = d_in[3];
    const void* Wv = d_in[4];
    const void* Wo = d_in[5];

    prep_kernel<<<NB_PREP, 256, 0, stream>>>(
        (const u32*)X, mask, Wq, Wk, Wv, Wo, Xbf, WqT, WkT, WvT, WoT, start);

    gemm_qkv_kernel<<<dim3(48, HID / 128), 256, 0, stream>>>(Xbf, WqT, Qbf, Kbf, Vtb);

    attn_kernel<<<dim3(S_LEN / 128, NH), 256, 0, stream>>>(Qbf, Kbf, Vtb, Obf, start);

    gemm_bt_kernel<3><<<dim3(HID / 64, S_LEN / 128), 256, 0, stream>>>(Obf, WoT, d_out, S_LEN, HID, HID, 1.f);
}